// Round 1
// baseline (960.331 us; speedup 1.0000x reference)
//
#include <hip/hip_runtime.h>
#include <math.h>

#define LB __launch_bounds__(256)

// Problem constants
// B=8, DIM=128, C=32, DI=64, H=W=64, L=4096, K=4, N=16, R=2, G=64 chunks of 64
static __device__ __forceinline__ float silu_f(float x){ return x / (1.f + __expf(-x)); }

// ---------------- axial depthwise: mw(1x7) -> mh(7x1) -> c(3x3), all dilated, + skip ----
__global__ LB void axial_kernel(const float* __restrict__ x, int c_off,
    const float* __restrict__ mh_w, const float* __restrict__ mh_b,
    const float* __restrict__ mw_w, const float* __restrict__ mw_b,
    const float* __restrict__ cw, const float* __restrict__ cb,
    int dil, float* __restrict__ acc)
{
    __shared__ float s0[4096];
    __shared__ float s1[4096];
    const int bc = blockIdx.x;        // b*32 + c
    const int b = bc >> 5, c = bc & 31;
    const int tid = threadIdx.x;
    const float* xin = x + ((size_t)(b*128 + c_off + c)) * 4096;
    float orig[16];
    #pragma unroll
    for (int kk=0;kk<16;++kk){ float v=xin[tid+kk*256]; orig[kk]=v; s0[tid+kk*256]=v; }
    __syncthreads();

    // horizontal 1x7
    float w7[7];
    #pragma unroll
    for (int t=0;t<7;++t) w7[t]=mw_w[c*7+t];
    float bias = mw_b[c];
    float v[16];
    #pragma unroll
    for (int kk=0;kk<16;++kk){
        int p=tid+kk*256, i=p>>6, j=p&63;
        float s=bias;
        #pragma unroll
        for (int t=0;t<7;++t){ int jj=j+(t-3)*dil; if (jj>=0&&jj<64) s+=s0[i*64+jj]*w7[t]; }
        v[kk]=s;
    }
    #pragma unroll
    for (int kk=0;kk<16;++kk) s1[tid+kk*256]=v[kk];
    __syncthreads();   // s1 ready; also guarantees all s0 reads (done before this point) finished

    // vertical 7x1
    #pragma unroll
    for (int t=0;t<7;++t) w7[t]=mh_w[c*7+t];
    bias = mh_b[c];
    #pragma unroll
    for (int kk=0;kk<16;++kk){
        int p=tid+kk*256, i=p>>6, j=p&63;
        float s=bias;
        #pragma unroll
        for (int t=0;t<7;++t){ int ii=i+(t-3)*dil; if (ii>=0&&ii<64) s+=s1[ii*64+j]*w7[t]; }
        v[kk]=s;
    }
    #pragma unroll
    for (int kk=0;kk<16;++kk) s0[tid+kk*256]=v[kk];
    __syncthreads();

    // 3x3 dilated + skip
    float w9[9];
    #pragma unroll
    for (int t=0;t<9;++t) w9[t]=cw[c*9+t];
    bias = cb[c];
    float* aout = acc + ((size_t)(b*32+c))*4096;
    #pragma unroll
    for (int kk=0;kk<16;++kk){
        int p=tid+kk*256, i=p>>6, j=p&63;
        float s=bias;
        #pragma unroll
        for (int a=0;a<3;++a){
            int ii=i+(a-1)*dil; if (ii<0||ii>=64) continue;
            #pragma unroll
            for (int bb2=0;bb2<3;++bb2){
                int jj=j+(bb2-1)*dil; if (jj<0||jj>=64) continue;
                s += s0[ii*64+jj]*w9[a*3+bb2];
            }
        }
        aout[p] = s + orig[kk];
    }
}

// ---------------- LN(C=32) + in_proj (32 -> 128), split xc / z -------------------------
__global__ LB void lnproj_kernel(const float* __restrict__ acc,
    const float* __restrict__ ln_w, const float* __restrict__ ln_b,
    const float* __restrict__ in_proj_w,
    float* __restrict__ xc, float* __restrict__ z)
{
    __shared__ float s_w[128*32];
    const int tid = threadIdx.x;
    for (int i=tid;i<4096;i+=256) s_w[i]=in_proj_w[i];
    const int gid = blockIdx.x*256 + tid;
    const int b = gid >> 12, l = gid & 4095;
    float v[32];
    const float* ap = acc + (size_t)b*32*4096 + l;
    #pragma unroll
    for (int c=0;c<32;++c) v[c]=ap[c*4096];
    float mu=0.f;
    #pragma unroll
    for (int c=0;c<32;++c) mu+=v[c];
    mu *= (1.f/32.f);
    float var=0.f;
    #pragma unroll
    for (int c=0;c<32;++c){ float d=v[c]-mu; var+=d*d; }
    var *= (1.f/32.f);
    float rs = rsqrtf(var + 1e-5f);
    #pragma unroll
    for (int c=0;c<32;++c) v[c] = (v[c]-mu)*rs*ln_w[c] + ln_b[c];
    __syncthreads();
    float* xcp = xc + (size_t)b*64*4096 + l;
    float* zp  = z  + (size_t)b*64*4096 + l;
    for (int e=0;e<128;++e){
        float s=0.f;
        #pragma unroll
        for (int c=0;c<32;++c) s += s_w[e*32+c]*v[c];
        if (e<64) xcp[e*4096]=s; else zp[(e-64)*4096]=s;
    }
}

// ---------------- 3x3 dwconv (dil=1) + SiLU --------------------------------------------
__global__ LB void conv3_kernel(const float* __restrict__ xc,
    const float* __restrict__ conv_w, const float* __restrict__ conv_b,
    float* __restrict__ xconv)
{
    __shared__ float s0[4096];
    const int bd = blockIdx.x;  // b*64 + d
    const int d = bd & 63;
    const int tid = threadIdx.x;
    const float* in = xc + (size_t)bd*4096;
    #pragma unroll
    for (int kk=0;kk<16;++kk) s0[tid+kk*256]=in[tid+kk*256];
    __syncthreads();
    float w9[9];
    #pragma unroll
    for (int t=0;t<9;++t) w9[t]=conv_w[d*9+t];
    float bias = conv_b[d];
    float* outp = xconv + (size_t)bd*4096;
    #pragma unroll
    for (int kk=0;kk<16;++kk){
        int p=tid+kk*256, i=p>>6, j=p&63;
        float s=bias;
        #pragma unroll
        for (int a=0;a<3;++a){
            int ii=i+a-1; if (ii<0||ii>=64) continue;
            #pragma unroll
            for (int bb2=0;bb2<3;++bb2){
                int jj=j+bb2-1; if (jj<0||jj>=64) continue;
                s += s0[ii*64+jj]*w9[a*3+bb2];
            }
        }
        outp[p]=silu_f(s);
    }
}

// ---------------- per-plane 64x64 transpose --------------------------------------------
__global__ LB void transpose_kernel(const float* __restrict__ in, float* __restrict__ out)
{
    __shared__ float s[64*65];
    const int bd = blockIdx.x;
    const int tid = threadIdx.x;
    const float* ip = in + (size_t)bd*4096;
    #pragma unroll
    for (int kk=0;kk<16;++kk){ int p=tid+kk*256; s[(p>>6)*65+(p&63)] = ip[p]; }
    __syncthreads();
    float* op = out + (size_t)bd*4096;
    #pragma unroll
    for (int kk=0;kk<16;++kk){ int p=tid+kk*256; op[p] = s[(p&63)*65 + (p>>6)]; }
}

// ---------------- x_proj (64->34) + dt_proj (2->64) + softplus --------------------------
__global__ LB void proj_kernel(const float* __restrict__ xconv, const float* __restrict__ xconvT,
    const float* __restrict__ x_proj_w, const float* __restrict__ dt_proj_w,
    const float* __restrict__ dt_proj_b,
    float* __restrict__ delta, float* __restrict__ Bsb, float* __restrict__ Csb)
{
    __shared__ float s_w[34*64];
    __shared__ float s_dtw[128];
    __shared__ float s_dtb[64];
    const int blk = blockIdx.x;        // (b*4+k)*16 + tb
    const int tb = blk & 15, bk = blk >> 4;
    const int k = bk & 3, b = bk >> 2;
    const int tid = threadIdx.x;
    for (int i=tid;i<2176;i+=256) s_w[i]=x_proj_w[k*2176+i];
    if (tid < 128) s_dtw[tid]=dt_proj_w[k*128+tid];
    if (tid < 64)  s_dtb[tid]=dt_proj_b[k*64+tid];
    __syncthreads();
    const int t = tb*256 + tid;
    const float* src = (k & 1) ? xconvT : xconv;
    const int pos = (k & 2) ? (4095 - t) : t;
    const float* sp = src + (size_t)b*64*4096 + pos;
    float xv[64];
    #pragma unroll
    for (int d=0;d<64;++d) xv[d]=sp[d*4096];
    float dts0=0.f, dts1=0.f;
    #pragma unroll
    for (int d=0;d<64;++d){ dts0 += s_w[d]*xv[d]; dts1 += s_w[64+d]*xv[d]; }
    float* bsp = Bsb + ((size_t)bk*4096 + t)*16;
    float* csp = Csb + ((size_t)bk*4096 + t)*16;
    for (int c=0;c<16;++c){
        float sB=0.f, sC=0.f;
        #pragma unroll
        for (int d=0;d<64;++d){ sB += s_w[(2+c)*64+d]*xv[d]; sC += s_w[(18+c)*64+d]*xv[d]; }
        bsp[c]=sB; csp[c]=sC;
    }
    float* dp = delta + (size_t)bk*64*4096 + t;
    for (int d=0;d<64;++d){
        float dv = dts0*s_dtw[d*2] + dts1*s_dtw[d*2+1] + s_dtb[d];
        float spl = (dv > 20.f) ? dv : log1pf(__expf(dv));
        dp[d*4096]=spl;
    }
}

// ---------------- scan phase 1: per-chunk local scan, record (prod dA, h_local_end) ----
__global__ LB void scan1_kernel(const float* __restrict__ delta,
    const float* __restrict__ xconv, const float* __restrict__ xconvT,
    const float* __restrict__ Bsb, const float* __restrict__ A_log,
    float* __restrict__ Aprod, float* __restrict__ hloc)
{
    __shared__ float s_d[64*65];
    __shared__ float s_u[64*65];
    __shared__ float s_B[64*16];
    const int blk = blockIdx.x;      // (b*4+k)*64 + g
    const int g = blk & 63, bk = blk >> 6;
    const int k = bk & 3, b = bk >> 2;
    const int tid = threadIdx.x;
    const float* dbase = delta + (size_t)bk*64*4096 + g*64;
    for (int i=tid;i<4096;i+=256){ int d2=i>>6, t2=i&63; s_d[d2*65+t2]=dbase[(size_t)d2*4096+t2]; }
    const float* src = (k & 1) ? xconvT : xconv;
    const float* ub = src + (size_t)b*64*4096;
    if (k & 2){
        for (int i=tid;i<4096;i+=256){ int d2=i>>6,t2=i&63; s_u[d2*65+t2]=ub[(size_t)d2*4096 + 4095 - (g*64+t2)]; }
    } else {
        for (int i=tid;i<4096;i+=256){ int d2=i>>6,t2=i&63; s_u[d2*65+t2]=ub[(size_t)d2*4096 + g*64 + t2]; }
    }
    const float* Bb = Bsb + ((size_t)bk*4096 + g*64)*16;
    for (int i=tid;i<1024;i+=256) s_B[i]=Bb[i];
    __syncthreads();

    const int d = tid >> 2, nb = (tid & 3)*4;
    const float* Ab = A_log + (k*64+d)*16 + nb;
    float A0=-__expf(Ab[0]), A1=-__expf(Ab[1]), A2=-__expf(Ab[2]), A3=-__expf(Ab[3]);
    float h0=0,h1=0,h2=0,h3=0, p0=1,p1=1,p2=1,p3=1;
    #pragma unroll 4
    for (int t=0;t<64;++t){
        float dlt = s_d[d*65+t];
        float du  = dlt * s_u[d*65+t];
        float e0=__expf(dlt*A0), e1=__expf(dlt*A1), e2=__expf(dlt*A2), e3=__expf(dlt*A3);
        p0*=e0; p1*=e1; p2*=e2; p3*=e3;
        h0 = h0*e0 + du*s_B[t*16+nb+0];
        h1 = h1*e1 + du*s_B[t*16+nb+1];
        h2 = h2*e2 + du*s_B[t*16+nb+2];
        h3 = h3*e3 + du*s_B[t*16+nb+3];
    }
    const size_t o = ((size_t)bk*64 + g)*256 + tid;
    ((float4*)Aprod)[o] = make_float4(p0,p1,p2,p3);
    ((float4*)hloc )[o] = make_float4(h0,h1,h2,h3);
}

// ---------------- scan phase 2: sequential chunk combine -> per-chunk entry states -----
__global__ LB void scan2_kernel(const float* __restrict__ Aprod,
    const float* __restrict__ hloc, float* __restrict__ hin)
{
    const int j = blockIdx.x*256 + threadIdx.x;   // 0..32767 : (b,k,dn)
    const int bk = j >> 10, dn = j & 1023;
    float h = 0.f;
    for (int g=0; g<64; ++g){
        const size_t o = ((size_t)bk*64 + g)*1024 + dn;
        hin[o] = h;
        h = Aprod[o]*h + hloc[o];
    }
}

// ---------------- scan phase 3: replay with true entry state, emit y -------------------
__global__ LB void scan3_kernel(const float* __restrict__ delta,
    const float* __restrict__ xconv, const float* __restrict__ xconvT,
    const float* __restrict__ Bsb, const float* __restrict__ Csb,
    const float* __restrict__ A_log, const float* __restrict__ Dp,
    const float* __restrict__ hin, float* __restrict__ outy)
{
    __shared__ float s_d[64*65];
    __shared__ float s_u[64*65];
    __shared__ float s_B[64*16];
    __shared__ float s_C[64*16];
    __shared__ float s_y[64*65];
    const int blk = blockIdx.x;      // (b*4+k)*64 + g
    const int g = blk & 63, bk = blk >> 6;
    const int k = bk & 3, b = bk >> 2;
    const int tid = threadIdx.x;
    const float* dbase = delta + (size_t)bk*64*4096 + g*64;
    for (int i=tid;i<4096;i+=256){ int d2=i>>6, t2=i&63; s_d[d2*65+t2]=dbase[(size_t)d2*4096+t2]; }
    const float* src = (k & 1) ? xconvT : xconv;
    const float* ub = src + (size_t)b*64*4096;
    if (k & 2){
        for (int i=tid;i<4096;i+=256){ int d2=i>>6,t2=i&63; s_u[d2*65+t2]=ub[(size_t)d2*4096 + 4095 - (g*64+t2)]; }
    } else {
        for (int i=tid;i<4096;i+=256){ int d2=i>>6,t2=i&63; s_u[d2*65+t2]=ub[(size_t)d2*4096 + g*64 + t2]; }
    }
    const float* Bb = Bsb + ((size_t)bk*4096 + g*64)*16;
    const float* Cb = Csb + ((size_t)bk*4096 + g*64)*16;
    for (int i=tid;i<1024;i+=256){ s_B[i]=Bb[i]; s_C[i]=Cb[i]; }
    __syncthreads();

    const int d = tid >> 2, nb = (tid & 3)*4;
    const float* Ab = A_log + (k*64+d)*16 + nb;
    float A0=-__expf(Ab[0]), A1=-__expf(Ab[1]), A2=-__expf(Ab[2]), A3=-__expf(Ab[3]);
    float4 hv = ((const float4*)hin)[((size_t)bk*64+g)*256 + tid];
    float h0=hv.x, h1=hv.y, h2=hv.z, h3=hv.w;
    const float Dv = Dp[k*64+d];
    #pragma unroll 4
    for (int t=0;t<64;++t){
        float dlt = s_d[d*65+t];
        float uu  = s_u[d*65+t];
        float du  = dlt*uu;
        float e0=__expf(dlt*A0), e1=__expf(dlt*A1), e2=__expf(dlt*A2), e3=__expf(dlt*A3);
        h0 = h0*e0 + du*s_B[t*16+nb+0];
        h1 = h1*e1 + du*s_B[t*16+nb+1];
        h2 = h2*e2 + du*s_B[t*16+nb+2];
        h3 = h3*e3 + du*s_B[t*16+nb+3];
        float part = h0*s_C[t*16+nb+0] + h1*s_C[t*16+nb+1]
                   + h2*s_C[t*16+nb+2] + h3*s_C[t*16+nb+3];
        part += __shfl_xor(part, 1);
        part += __shfl_xor(part, 2);
        if ((tid & 3) == 0) s_y[d*65+t] = part + Dv*uu;
    }
    __syncthreads();
    float* ob = outy + (size_t)bk*64*4096 + g*64;
    for (int i=tid;i<4096;i+=256){ int d2=i>>6,t2=i&63; ob[(size_t)d2*4096+t2]=s_y[d2*65+t2]; }
}

// ---------------- direction-combine + out LN + gate + out_proj + skip + BN + ReLU ------
__global__ LB void combine_kernel(const float* __restrict__ outy,
    const float* __restrict__ z, const float* __restrict__ acc,
    const float* __restrict__ onw, const float* __restrict__ onb,
    const float* __restrict__ opw,
    const float* __restrict__ bn_g, const float* __restrict__ bn_b,
    const float* __restrict__ bn_m, const float* __restrict__ bn_v,
    int c_off, float* __restrict__ out)
{
    __shared__ float s_pw[32*64];
    const int tid = threadIdx.x;
    for (int i=tid;i<2048;i+=256) s_pw[i]=opw[i];
    __syncthreads();
    const int gid = blockIdx.x*256 + tid;
    const int b = gid >> 12, l = gid & 4095;
    const int lT = (l & 63)*64 + (l >> 6);
    const float* oy = outy + (size_t)b*4*64*4096;
    float y[64];
    #pragma unroll 8
    for (int d=0;d<64;++d){
        y[d] = oy[(size_t)(0*64+d)*4096 + l]
             + oy[(size_t)(2*64+d)*4096 + (4095-l)]
             + oy[(size_t)(1*64+d)*4096 + lT]
             + oy[(size_t)(3*64+d)*4096 + (4095-lT)];
    }
    float mu=0.f;
    #pragma unroll
    for (int d=0;d<64;++d) mu+=y[d];
    mu *= (1.f/64.f);
    float var=0.f;
    #pragma unroll
    for (int d=0;d<64;++d){ float t2=y[d]-mu; var+=t2*t2; }
    var *= (1.f/64.f);
    float rs = rsqrtf(var + 1e-5f);
    const float* zp = z + (size_t)b*64*4096 + l;
    #pragma unroll 8
    for (int d=0;d<64;++d){
        float t2 = (y[d]-mu)*rs*onw[d] + onb[d];
        float zv = zp[(size_t)d*4096];
        y[d] = t2 * silu_f(zv);
    }
    const float* ap = acc + (size_t)b*32*4096 + l;
    for (int c=0;c<32;++c){
        float s=0.f;
        #pragma unroll
        for (int d=0;d<64;++d) s += s_pw[c*64+d]*y[d];
        s += ap[(size_t)c*4096];
        const int ch = c_off + c;
        float bnv = (s - bn_m[ch])*rsqrtf(bn_v[ch]+1e-5f)*bn_g[ch] + bn_b[ch];
        out[((size_t)b*128+ch)*4096 + l] = fmaxf(bnv, 0.f);
    }
}

// ---------------- chunk 4 passthrough: BN + ReLU ----------------------------------------
__global__ LB void bnpass_kernel(const float* __restrict__ x,
    const float* __restrict__ bn_g, const float* __restrict__ bn_b,
    const float* __restrict__ bn_m, const float* __restrict__ bn_v,
    float* __restrict__ out)
{
    const int gid = blockIdx.x*256 + threadIdx.x;   // B*32*4096
    const int l = gid & 4095, bc = gid >> 12;
    const int c = bc & 31, b = bc >> 5;
    const int ch = 96 + c;
    const size_t idx = ((size_t)b*128+ch)*4096 + l;
    float v = x[idx];
    float r = (v - bn_m[ch])*rsqrtf(bn_v[ch]+1e-5f)*bn_g[ch] + bn_b[ch];
    out[idx] = fmaxf(r, 0.f);
}

extern "C" void kernel_launch(void* const* d_in, const int* in_sizes, int n_in,
                              void* d_out, int out_size, void* d_ws, size_t ws_size,
                              hipStream_t stream) {
    const float* x         = (const float*)d_in[0];
    const float* ln_w      = (const float*)d_in[19];
    const float* ln_b      = (const float*)d_in[20];
    const float* in_proj_w = (const float*)d_in[21];
    const float* conv_w    = (const float*)d_in[22];
    const float* conv_b    = (const float*)d_in[23];
    const float* x_proj_w  = (const float*)d_in[24];
    const float* dt_proj_w = (const float*)d_in[25];
    const float* dt_proj_b = (const float*)d_in[26];
    const float* A_log     = (const float*)d_in[27];
    const float* Dp        = (const float*)d_in[28];
    const float* onw       = (const float*)d_in[29];
    const float* onb       = (const float*)d_in[30];
    const float* opw       = (const float*)d_in[31];
    const float* bn_g      = (const float*)d_in[32];
    const float* bn_b      = (const float*)d_in[33];
    const float* bn_m      = (const float*)d_in[34];
    const float* bn_v      = (const float*)d_in[35];
    float* out = (float*)d_out;

    float* ws = (float*)d_ws;
    float* acc    = ws;                  // 1,048,576
    float* xc     = acc    + 1048576;    // 2,097,152
    float* z      = xc     + 2097152;    // 2,097,152
    float* xconv  = z      + 2097152;    // 2,097,152
    float* xconvT = xconv  + 2097152;    // 2,097,152
    float* delta  = xconvT + 2097152;    // 8,388,608
    float* Bsb    = delta  + 8388608;    // 2,097,152
    float* Csb    = Bsb    + 2097152;    // 2,097,152
    float* Apr    = Csb    + 2097152;    // 2,097,152
    float* hlo    = Apr    + 2097152;    // 2,097,152
    float* hin    = hlo    + 2097152;    // 2,097,152
    float* outy   = hin    + 2097152;    // 8,388,608

    // chunk 4: raw passthrough with BN+ReLU
    bnpass_kernel<<<4096, 256, 0, stream>>>(x, bn_g, bn_b, bn_m, bn_v, out);

    for (int chunk=0; chunk<3; ++chunk){
        const int base = 1 + chunk*6;
        const float* mh_w = (const float*)d_in[base+0];
        const float* mh_b = (const float*)d_in[base+1];
        const float* mw_w = (const float*)d_in[base+2];
        const float* mw_b = (const float*)d_in[base+3];
        const float* c_w  = (const float*)d_in[base+4];
        const float* c_b  = (const float*)d_in[base+5];
        const int dil = chunk + 1;
        const int c_off = chunk*32;

        axial_kernel<<<256, 256, 0, stream>>>(x, c_off, mh_w, mh_b, mw_w, mw_b, c_w, c_b, dil, acc);
        lnproj_kernel<<<128, 256, 0, stream>>>(acc, ln_w, ln_b, in_proj_w, xc, z);
        conv3_kernel<<<512, 256, 0, stream>>>(xc, conv_w, conv_b, xconv);
        transpose_kernel<<<512, 256, 0, stream>>>(xconv, xconvT);
        proj_kernel<<<512, 256, 0, stream>>>(xconv, xconvT, x_proj_w, dt_proj_w, dt_proj_b,
                                             delta, Bsb, Csb);
        scan1_kernel<<<2048, 256, 0, stream>>>(delta, xconv, xconvT, Bsb, A_log, Apr, hlo);
        scan2_kernel<<<128, 256, 0, stream>>>(Apr, hlo, hin);
        scan3_kernel<<<2048, 256, 0, stream>>>(delta, xconv, xconvT, Bsb, Csb, A_log, Dp, hin, outy);
        combine_kernel<<<128, 256, 0, stream>>>(outy, z, acc, onw, onb, opw,
                                                bn_g, bn_b, bn_m, bn_v, c_off, out);
    }
}

// Round 2
// 609.743 us; speedup vs baseline: 1.5750x; 1.5750x over previous
//
#include <hip/hip_runtime.h>
#include <math.h>

#define LB __launch_bounds__(256)
#define LB512 __launch_bounds__(512)

// B=8, DIM=128, C=32, DI=64, H=W=64, L=4096, K=4, N=16, R=2, G=64 chunks of 64
static __device__ __forceinline__ float silu_f(float x){ return x / (1.f + __expf(-x)); }

// ---------------- axial depthwise: mw(1x7) -> mh(7x1) -> c(3x3), all dilated, + skip ----
__global__ LB void axial_kernel(const float* __restrict__ x, int c_off,
    const float* __restrict__ mh_w, const float* __restrict__ mh_b,
    const float* __restrict__ mw_w, const float* __restrict__ mw_b,
    const float* __restrict__ cw, const float* __restrict__ cb,
    int dil, float* __restrict__ acc)
{
    __shared__ float s0[4096];
    __shared__ float s1[4096];
    const int bc = blockIdx.x;        // b*32 + c
    const int b = bc >> 5, c = bc & 31;
    const int tid = threadIdx.x;
    const float* xin = x + ((size_t)(b*128 + c_off + c)) * 4096;
    float orig[16];
    #pragma unroll
    for (int kk=0;kk<16;++kk){ float v=xin[tid+kk*256]; orig[kk]=v; s0[tid+kk*256]=v; }
    __syncthreads();

    // horizontal 1x7
    float w7[7];
    #pragma unroll
    for (int t=0;t<7;++t) w7[t]=mw_w[c*7+t];
    float bias = mw_b[c];
    float v[16];
    #pragma unroll
    for (int kk=0;kk<16;++kk){
        int p=tid+kk*256, i=p>>6, j=p&63;
        float s=bias;
        #pragma unroll
        for (int t=0;t<7;++t){ int jj=j+(t-3)*dil; if (jj>=0&&jj<64) s+=s0[i*64+jj]*w7[t]; }
        v[kk]=s;
    }
    #pragma unroll
    for (int kk=0;kk<16;++kk) s1[tid+kk*256]=v[kk];
    __syncthreads();

    // vertical 7x1
    #pragma unroll
    for (int t=0;t<7;++t) w7[t]=mh_w[c*7+t];
    bias = mh_b[c];
    #pragma unroll
    for (int kk=0;kk<16;++kk){
        int p=tid+kk*256, i=p>>6, j=p&63;
        float s=bias;
        #pragma unroll
        for (int t=0;t<7;++t){ int ii=i+(t-3)*dil; if (ii>=0&&ii<64) s+=s1[ii*64+j]*w7[t]; }
        v[kk]=s;
    }
    __syncthreads();
    #pragma unroll
    for (int kk=0;kk<16;++kk) s0[tid+kk*256]=v[kk];
    __syncthreads();

    // 3x3 dilated + skip
    float w9[9];
    #pragma unroll
    for (int t=0;t<9;++t) w9[t]=cw[c*9+t];
    bias = cb[c];
    float* aout = acc + ((size_t)(b*32+c))*4096;
    #pragma unroll
    for (int kk=0;kk<16;++kk){
        int p=tid+kk*256, i=p>>6, j=p&63;
        float s=bias;
        #pragma unroll
        for (int a=0;a<3;++a){
            int ii=i+(a-1)*dil; if (ii<0||ii>=64) continue;
            #pragma unroll
            for (int bb2=0;bb2<3;++bb2){
                int jj=j+(bb2-1)*dil; if (jj<0||jj>=64) continue;
                s += s0[ii*64+jj]*w9[a*3+bb2];
            }
        }
        aout[p] = s + orig[kk];
    }
}

// ---------------- LN(C=32) + in_proj (32 -> 128), split xc / z -------------------------
// grid 512 = b*64 + lt (64-l tile); 512 threads = 64 l x 8 groups of 16 e-rows
__global__ LB512 void lnproj_kernel(const float* __restrict__ acc,
    const float* __restrict__ ln_w, const float* __restrict__ ln_b,
    const float* __restrict__ in_proj_w,
    float* __restrict__ xc, float* __restrict__ z)
{
    __shared__ float s_a[32*65];
    const int b = blockIdx.x >> 6, lt = blockIdx.x & 63;
    const int l0 = lt*64;
    const int tid = threadIdx.x;
    const float* ab = acc + (size_t)b*32*4096 + l0;
    for (int i=tid;i<2048;i+=512){ int c=i>>6, j=i&63; s_a[c*65+j]=ab[(size_t)c*4096 + j]; }
    __syncthreads();
    const int l = tid & 63;
    const int g = __builtin_amdgcn_readfirstlane(tid >> 6);   // wave-uniform (512 thr)
    float v[32];
    float mu=0.f;
    #pragma unroll
    for (int c=0;c<32;++c){ v[c]=s_a[c*65+l]; mu+=v[c]; }
    mu *= (1.f/32.f);
    float var=0.f;
    #pragma unroll
    for (int c=0;c<32;++c){ float d2=v[c]-mu; var+=d2*d2; }
    var *= (1.f/32.f);
    float rs = rsqrtf(var+1e-5f);
    #pragma unroll
    for (int c=0;c<32;++c) v[c] = (v[c]-mu)*rs*ln_w[c] + ln_b[c];
    float* xcp = xc + (size_t)b*64*4096 + l0 + l;
    float* zp  = z  + (size_t)b*64*4096 + l0 + l;
    for (int e=g*16; e<g*16+16; ++e){
        const float* wr = in_proj_w + e*32;   // uniform rows -> scalar loads
        float s=0.f;
        #pragma unroll
        for (int c=0;c<32;++c) s += wr[c]*v[c];
        if (e<64) xcp[(size_t)e*4096]=s; else zp[(size_t)(e-64)*4096]=s;
    }
}

// ---------------- 3x3 dwconv (dil=1) + SiLU, fused transpose output --------------------
__global__ LB void conv3_kernel(const float* __restrict__ xc,
    const float* __restrict__ conv_w, const float* __restrict__ conv_b,
    float* __restrict__ xconv, float* __restrict__ xconvT)
{
    __shared__ float s0[4096];
    __shared__ float s1[64*65];
    const int bd = blockIdx.x;  // b*64 + d
    const int d = bd & 63;
    const int tid = threadIdx.x;
    const float* in = xc + (size_t)bd*4096;
    #pragma unroll
    for (int kk=0;kk<16;++kk) s0[tid+kk*256]=in[tid+kk*256];
    __syncthreads();
    float w9[9];
    #pragma unroll
    for (int t=0;t<9;++t) w9[t]=conv_w[d*9+t];
    float bias = conv_b[d];
    float* outp = xconv + (size_t)bd*4096;
    #pragma unroll
    for (int kk=0;kk<16;++kk){
        int p=tid+kk*256, i=p>>6, j=p&63;
        float s=bias;
        #pragma unroll
        for (int a=0;a<3;++a){
            int ii=i+a-1; if (ii<0||ii>=64) continue;
            #pragma unroll
            for (int bb2=0;bb2<3;++bb2){
                int jj=j+bb2-1; if (jj<0||jj>=64) continue;
                s += s0[ii*64+jj]*w9[a*3+bb2];
            }
        }
        s = silu_f(s);
        outp[p]=s;
        s1[i*65+j]=s;
    }
    __syncthreads();
    float* outT = xconvT + (size_t)bd*4096;
    #pragma unroll
    for (int kk=0;kk<16;++kk){ int p=tid+kk*256; outT[p] = s1[(p&63)*65 + (p>>6)]; }
}

// ---------------- x_proj (64->34) + dt_proj (2->64) + softplus --------------------------
// grid 2048 = (b*4+k)*64 + tt (64-t tile); 256 thr = 64 t x 4 groups of 9 rows
__global__ LB void proj_kernel(const float* __restrict__ xconv, const float* __restrict__ xconvT,
    const float* __restrict__ x_proj_w, const float* __restrict__ dt_proj_w,
    const float* __restrict__ dt_proj_b,
    float* __restrict__ delta, float* __restrict__ Bsb, float* __restrict__ Csb)
{
    __shared__ float s_x[64*65];     // [t][d] pad 65
    __shared__ float s_dts[2][64];
    const int blk = blockIdx.x;
    const int tt = blk & 63, bk = blk >> 6;
    const int k = bk & 3, b = bk >> 2;
    const int tid = threadIdx.x;
    const int t0 = tt*64;
    const float* src = (k & 1) ? xconvT : xconv;
    const float* sb = src + (size_t)b*64*4096;
    for (int i=tid;i<4096;i+=256){
        int d=i>>6, j=i&63;
        int col = (k&2) ? (4095-(t0+j)) : (t0+j);
        s_x[j*65+d] = sb[(size_t)d*4096 + col];
    }
    __syncthreads();
    const int t = tid & 63;
    const int q = __builtin_amdgcn_readfirstlane(tid >> 6);   // wave-uniform
    const float* wp = x_proj_w + k*2176;
    float acc9[9];
    #pragma unroll
    for (int r=0;r<9;++r) acc9[r]=0.f;
    const int r0 = q*9;
    const int nr = (q==3)?7:9;
    for (int ch=0; ch<4; ++ch){
        float xv[16];
        #pragma unroll
        for (int i=0;i<16;++i) xv[i] = s_x[t*65 + ch*16 + i];
        #pragma unroll
        for (int r=0;r<9;++r){
            if (r < nr){
                const float* wr = wp + (r0+r)*64 + ch*16;   // uniform -> scalar loads
                float s=0.f;
                #pragma unroll
                for (int i=0;i<16;++i) s += wr[i]*xv[i];
                acc9[r] += s;
            }
        }
    }
    #pragma unroll
    for (int r=0;r<9;++r){
        if (r<nr){
            int row = r0 + r;
            if (row < 2) s_dts[row][t] = acc9[r];
            else if (row < 18) Bsb[((size_t)bk*4096 + t0+t)*16 + (row-2)] = acc9[r];
            else               Csb[((size_t)bk*4096 + t0+t)*16 + (row-18)] = acc9[r];
        }
    }
    __syncthreads();
    const float dts0 = s_dts[0][t], dts1 = s_dts[1][t];
    const float* dwp = dt_proj_w + k*128;
    const float* dbp = dt_proj_b + k*64;
    float* dp = delta + (size_t)bk*64*4096 + t0 + t;
    #pragma unroll
    for (int i=0;i<16;++i){
        int d = q*16 + i;
        float dv = dts0*dwp[d*2] + dts1*dwp[d*2+1] + dbp[d];
        float spl = (dv > 20.f) ? dv : log1pf(__expf(dv));
        dp[(size_t)d*4096] = spl;
    }
}

// ---------------- scan phase 1: per-chunk local scan, record (prod dA, h_local_end) ----
__global__ LB void scan1_kernel(const float* __restrict__ delta,
    const float* __restrict__ xconv, const float* __restrict__ xconvT,
    const float* __restrict__ Bsb, const float* __restrict__ A_log,
    float* __restrict__ Aprod, float* __restrict__ hloc)
{
    __shared__ float s_d[64*65];
    __shared__ float s_u[64*65];
    __shared__ float s_B[64*16];
    const int blk = blockIdx.x;      // (b*4+k)*64 + g
    const int g = blk & 63, bk = blk >> 6;
    const int k = bk & 3, b = bk >> 2;
    const int tid = threadIdx.x;
    const float* dbase = delta + (size_t)bk*64*4096 + g*64;
    for (int i=tid;i<4096;i+=256){ int d2=i>>6, t2=i&63; s_d[d2*65+t2]=dbase[(size_t)d2*4096+t2]; }
    const float* src = (k & 1) ? xconvT : xconv;
    const float* ub = src + (size_t)b*64*4096;
    if (k & 2){
        for (int i=tid;i<4096;i+=256){ int d2=i>>6,t2=i&63; s_u[d2*65+t2]=ub[(size_t)d2*4096 + 4095 - (g*64+t2)]; }
    } else {
        for (int i=tid;i<4096;i+=256){ int d2=i>>6,t2=i&63; s_u[d2*65+t2]=ub[(size_t)d2*4096 + g*64 + t2]; }
    }
    const float* Bb = Bsb + ((size_t)bk*4096 + g*64)*16;
    for (int i=tid;i<1024;i+=256) s_B[i]=Bb[i];
    __syncthreads();

    const int d = tid >> 2, nb = (tid & 3)*4;
    const float* Ab = A_log + (k*64+d)*16 + nb;
    float A0=-__expf(Ab[0]), A1=-__expf(Ab[1]), A2=-__expf(Ab[2]), A3=-__expf(Ab[3]);
    float h0=0,h1=0,h2=0,h3=0, p0=1,p1=1,p2=1,p3=1;
    #pragma unroll 4
    for (int t=0;t<64;++t){
        float dlt = s_d[d*65+t];
        float du  = dlt * s_u[d*65+t];
        float e0=__expf(dlt*A0), e1=__expf(dlt*A1), e2=__expf(dlt*A2), e3=__expf(dlt*A3);
        p0*=e0; p1*=e1; p2*=e2; p3*=e3;
        h0 = h0*e0 + du*s_B[t*16+nb+0];
        h1 = h1*e1 + du*s_B[t*16+nb+1];
        h2 = h2*e2 + du*s_B[t*16+nb+2];
        h3 = h3*e3 + du*s_B[t*16+nb+3];
    }
    const size_t o = ((size_t)bk*64 + g)*256 + tid;
    ((float4*)Aprod)[o] = make_float4(p0,p1,p2,p3);
    ((float4*)hloc )[o] = make_float4(h0,h1,h2,h3);
}

// ---------------- scan phase 2: sequential chunk combine -> per-chunk entry states -----
__global__ LB void scan2_kernel(const float* __restrict__ Aprod,
    const float* __restrict__ hloc, float* __restrict__ hin)
{
    const int j = blockIdx.x*256 + threadIdx.x;   // 0..32767 : (b,k,dn)
    const int bk = j >> 10, dn = j & 1023;
    float h = 0.f;
    for (int g=0; g<64; ++g){
        const size_t o = ((size_t)bk*64 + g)*1024 + dn;
        hin[o] = h;
        h = Aprod[o]*h + hloc[o];
    }
}

// ---------------- scan phase 3: replay with true entry state, emit y -------------------
__global__ LB void scan3_kernel(const float* __restrict__ delta,
    const float* __restrict__ xconv, const float* __restrict__ xconvT,
    const float* __restrict__ Bsb, const float* __restrict__ Csb,
    const float* __restrict__ A_log, const float* __restrict__ Dp,
    const float* __restrict__ hin, float* __restrict__ outy)
{
    __shared__ float s_d[64*65];    // delta tile; re-used in-place as y tile
    __shared__ float s_u[64*65];
    __shared__ float s_B[64*16];
    __shared__ float s_C[64*16];
    const int blk = blockIdx.x;      // (b*4+k)*64 + g
    const int g = blk & 63, bk = blk >> 6;
    const int k = bk & 3, b = bk >> 2;
    const int tid = threadIdx.x;
    const float* dbase = delta + (size_t)bk*64*4096 + g*64;
    for (int i=tid;i<4096;i+=256){ int d2=i>>6, t2=i&63; s_d[d2*65+t2]=dbase[(size_t)d2*4096+t2]; }
    const float* src = (k & 1) ? xconvT : xconv;
    const float* ub = src + (size_t)b*64*4096;
    if (k & 2){
        for (int i=tid;i<4096;i+=256){ int d2=i>>6,t2=i&63; s_u[d2*65+t2]=ub[(size_t)d2*4096 + 4095 - (g*64+t2)]; }
    } else {
        for (int i=tid;i<4096;i+=256){ int d2=i>>6,t2=i&63; s_u[d2*65+t2]=ub[(size_t)d2*4096 + g*64 + t2]; }
    }
    const float* Bb = Bsb + ((size_t)bk*4096 + g*64)*16;
    const float* Cb = Csb + ((size_t)bk*4096 + g*64)*16;
    for (int i=tid;i<1024;i+=256){ s_B[i]=Bb[i]; s_C[i]=Cb[i]; }
    __syncthreads();

    const int d = tid >> 2, nb = (tid & 3)*4;
    const float* Ab = A_log + (k*64+d)*16 + nb;
    float A0=-__expf(Ab[0]), A1=-__expf(Ab[1]), A2=-__expf(Ab[2]), A3=-__expf(Ab[3]);
    float4 hv = ((const float4*)hin)[((size_t)bk*64+g)*256 + tid];
    float h0=hv.x, h1=hv.y, h2=hv.z, h3=hv.w;
    const float Dv = Dp[k*64+d];
    #pragma unroll 4
    for (int t=0;t<64;++t){
        float dlt = s_d[d*65+t];
        float uu  = s_u[d*65+t];
        float du  = dlt*uu;
        float e0=__expf(dlt*A0), e1=__expf(dlt*A1), e2=__expf(dlt*A2), e3=__expf(dlt*A3);
        h0 = h0*e0 + du*s_B[t*16+nb+0];
        h1 = h1*e1 + du*s_B[t*16+nb+1];
        h2 = h2*e2 + du*s_B[t*16+nb+2];
        h3 = h3*e3 + du*s_B[t*16+nb+3];
        float part = h0*s_C[t*16+nb+0] + h1*s_C[t*16+nb+1]
                   + h2*s_C[t*16+nb+2] + h3*s_C[t*16+nb+3];
        part += __shfl_xor(part, 1);
        part += __shfl_xor(part, 2);
        if ((tid & 3) == 0) s_d[d*65+t] = part + Dv*uu;   // overwrite consumed delta cell
    }
    __syncthreads();
    float* ob = outy + (size_t)bk*64*4096 + g*64;
    for (int i=tid;i<4096;i+=256){ int d2=i>>6,t2=i&63; ob[(size_t)d2*4096+t2]=s_d[d2*65+t2]; }
}

// ---------------- transpose dir-1 / dir-3 planes of outy -------------------------------
// grid 1024 = kk*512 + b*64 + d
__global__ LB void outyT_kernel(const float* __restrict__ outy, float* __restrict__ outyT)
{
    __shared__ float s[64*65];
    const int p = blockIdx.x;
    const int kk = p >> 9, bd = p & 511;
    const int b = bd >> 6, d = bd & 63;
    const float* ip = outy + ((size_t)(b*4 + (kk?3:1))*64 + d)*4096;
    const int tid = threadIdx.x;
    #pragma unroll
    for (int k2=0;k2<16;++k2){ int pp=tid+k2*256; s[(pp>>6)*65+(pp&63)] = ip[pp]; }
    __syncthreads();
    float* op = outyT + ((size_t)(kk*8+b)*64 + d)*4096;
    #pragma unroll
    for (int k2=0;k2<16;++k2){ int pp=tid+k2*256; op[pp] = s[(pp&63)*65 + (pp>>6)]; }
}

// ---------------- direction-combine + out LN + gate + out_proj + skip + BN + ReLU ------
// grid 512 = b*64 + lt; 512 thr = 64 l x 8 groups (8 d each, 4 c each)
__global__ LB512 void combine_kernel(const float* __restrict__ outy,
    const float* __restrict__ outyT,
    const float* __restrict__ z, const float* __restrict__ acc,
    const float* __restrict__ onw, const float* __restrict__ onb,
    const float* __restrict__ opw,
    const float* __restrict__ bn_g, const float* __restrict__ bn_b,
    const float* __restrict__ bn_m, const float* __restrict__ bn_v,
    int c_off, float* __restrict__ out)
{
    __shared__ float s_red[2][8][64];
    __shared__ float s_y[64*65];
    const int b = blockIdx.x >> 6, lt = blockIdx.x & 63;
    const int l0 = lt*64;
    const int tid = threadIdx.x;
    const int l = tid & 63;
    const int g = __builtin_amdgcn_readfirstlane(tid >> 6);
    const float* o0 = outy  + (size_t)(b*4+0)*64*4096;
    const float* o2 = outy  + (size_t)(b*4+2)*64*4096;
    const float* T1 = outyT + (size_t)(0*8+b)*64*4096;
    const float* T3 = outyT + (size_t)(1*8+b)*64*4096;
    const int lf = l0 + l;
    const int lr = 4095 - lf;
    float y[8];
    float psum=0.f, psq=0.f;
    #pragma unroll
    for (int i=0;i<8;++i){
        int d = g*8+i;
        float vv = o0[(size_t)d*4096 + lf] + o2[(size_t)d*4096 + lr]
                 + T1[(size_t)d*4096 + lf] + T3[(size_t)d*4096 + lr];
        y[i]=vv; psum+=vv; psq+=vv*vv;
    }
    s_red[0][g][l]=psum; s_red[1][g][l]=psq;
    __syncthreads();
    float mu=0.f, vsum=0.f;
    #pragma unroll
    for (int gg=0;gg<8;++gg){ mu += s_red[0][gg][l]; vsum += s_red[1][gg][l]; }
    mu *= (1.f/64.f);
    float var = vsum*(1.f/64.f) - mu*mu;
    float rs = rsqrtf(var + 1e-5f);
    const float* zp = z + (size_t)b*64*4096 + lf;
    #pragma unroll
    for (int i=0;i<8;++i){
        int d = g*8+i;
        float t2 = (y[i]-mu)*rs*onw[d] + onb[d];
        float zv = zp[(size_t)d*4096];
        s_y[l*65 + d] = t2 * silu_f(zv);
    }
    __syncthreads();
    float a4[4] = {0.f,0.f,0.f,0.f};
    for (int d=0; d<64; ++d){
        float xval = s_y[l*65+d];
        #pragma unroll
        for (int j=0;j<4;++j) a4[j] += opw[(g*4+j)*64+d]*xval;   // uniform -> scalar loads
    }
    const float* ap = acc + (size_t)b*32*4096 + lf;
    #pragma unroll
    for (int j=0;j<4;++j){
        int c = g*4+j, ch = c_off+c;
        float s = a4[j] + ap[(size_t)c*4096];
        float bnv = (s - bn_m[ch])*rsqrtf(bn_v[ch]+1e-5f)*bn_g[ch] + bn_b[ch];
        out[((size_t)b*128+ch)*4096 + lf] = fmaxf(bnv, 0.f);
    }
}

// ---------------- chunk 4 passthrough: BN + ReLU ----------------------------------------
__global__ LB void bnpass_kernel(const float* __restrict__ x,
    const float* __restrict__ bn_g, const float* __restrict__ bn_b,
    const float* __restrict__ bn_m, const float* __restrict__ bn_v,
    float* __restrict__ out)
{
    const int gid = blockIdx.x*256 + threadIdx.x;   // B*32*4096
    const int l = gid & 4095, bc = gid >> 12;
    const int c = bc & 31, b = bc >> 5;
    const int ch = 96 + c;
    const size_t idx = ((size_t)b*128+ch)*4096 + l;
    float v = x[idx];
    float r = (v - bn_m[ch])*rsqrtf(bn_v[ch]+1e-5f)*bn_g[ch] + bn_b[ch];
    out[idx] = fmaxf(r, 0.f);
}

extern "C" void kernel_launch(void* const* d_in, const int* in_sizes, int n_in,
                              void* d_out, int out_size, void* d_ws, size_t ws_size,
                              hipStream_t stream) {
    const float* x         = (const float*)d_in[0];
    const float* ln_w      = (const float*)d_in[19];
    const float* ln_b      = (const float*)d_in[20];
    const float* in_proj_w = (const float*)d_in[21];
    const float* conv_w    = (const float*)d_in[22];
    const float* conv_b    = (const float*)d_in[23];
    const float* x_proj_w  = (const float*)d_in[24];
    const float* dt_proj_w = (const float*)d_in[25];
    const float* dt_proj_b = (const float*)d_in[26];
    const float* A_log     = (const float*)d_in[27];
    const float* Dp        = (const float*)d_in[28];
    const float* onw       = (const float*)d_in[29];
    const float* onb       = (const float*)d_in[30];
    const float* opw       = (const float*)d_in[31];
    const float* bn_g      = (const float*)d_in[32];
    const float* bn_b      = (const float*)d_in[33];
    const float* bn_m      = (const float*)d_in[34];
    const float* bn_v      = (const float*)d_in[35];
    float* out = (float*)d_out;

    float* ws = (float*)d_ws;
    float* acc    = ws;                  // 1,048,576
    float* xc     = acc    + 1048576;    // 2,097,152
    float* z      = xc     + 2097152;    // 2,097,152
    float* xconv  = z      + 2097152;    // 2,097,152
    float* xconvT = xconv  + 2097152;    // 2,097,152
    float* delta  = xconvT + 2097152;    // 8,388,608
    float* Bsb    = delta  + 8388608;    // 2,097,152
    float* Csb    = Bsb    + 2097152;    // 2,097,152
    float* Apr    = Csb    + 2097152;    // 2,097,152
    float* hlo    = Apr    + 2097152;    // 2,097,152
    float* hin    = hlo    + 2097152;    // 2,097,152
    float* outy   = hin    + 2097152;    // 8,388,608
    float* outyT  = delta;               // alias: delta dead after scan3, rewritten next chunk

    // chunk 4: raw passthrough with BN+ReLU
    bnpass_kernel<<<4096, 256, 0, stream>>>(x, bn_g, bn_b, bn_m, bn_v, out);

    for (int chunk=0; chunk<3; ++chunk){
        const int base = 1 + chunk*6;
        const float* mh_w = (const float*)d_in[base+0];
        const float* mh_b = (const float*)d_in[base+1];
        const float* mw_w = (const float*)d_in[base+2];
        const float* mw_b = (const float*)d_in[base+3];
        const float* c_w  = (const float*)d_in[base+4];
        const float* c_b  = (const float*)d_in[base+5];
        const int dil = chunk + 1;
        const int c_off = chunk*32;

        axial_kernel<<<256, 256, 0, stream>>>(x, c_off, mh_w, mh_b, mw_w, mw_b, c_w, c_b, dil, acc);
        lnproj_kernel<<<512, 512, 0, stream>>>(acc, ln_w, ln_b, in_proj_w, xc, z);
        conv3_kernel<<<512, 256, 0, stream>>>(xc, conv_w, conv_b, xconv, xconvT);
        proj_kernel<<<2048, 256, 0, stream>>>(xconv, xconvT, x_proj_w, dt_proj_w, dt_proj_b,
                                              delta, Bsb, Csb);
        scan1_kernel<<<2048, 256, 0, stream>>>(delta, xconv, xconvT, Bsb, A_log, Apr, hlo);
        scan2_kernel<<<128, 256, 0, stream>>>(Apr, hlo, hin);
        scan3_kernel<<<2048, 256, 0, stream>>>(delta, xconv, xconvT, Bsb, Csb, A_log, Dp, hin, outy);
        outyT_kernel<<<1024, 256, 0, stream>>>(outy, outyT);
        combine_kernel<<<512, 512, 0, stream>>>(outy, outyT, z, acc, onw, onb, opw,
                                                bn_g, bn_b, bn_m, bn_v, c_off, out);
    }
}

// Round 3
// 595.915 us; speedup vs baseline: 1.6115x; 1.0232x over previous
//
#include <hip/hip_runtime.h>
#include <math.h>

#define LB __launch_bounds__(256)
#define LB512 __launch_bounds__(512)

// B=8, DIM=128, C=32, DI=64, H=W=64, L=4096, K=4, N=16, R=2, G=64 chunks of 64
#define LOG2E 1.44269504088896340736f
static __device__ __forceinline__ float silu_f(float x){ return x / (1.f + __expf(-x)); }
static __device__ __forceinline__ float softplus_f(float x){
    return (x > 20.f) ? x : __logf(1.f + __expf(x));
}

// ---------------- axial depthwise: mw(1x7) -> mh(7x1) -> c(3x3), all dilated, + skip ----
__global__ LB void axial_kernel(const float* __restrict__ x, int c_off,
    const float* __restrict__ mh_w, const float* __restrict__ mh_b,
    const float* __restrict__ mw_w, const float* __restrict__ mw_b,
    const float* __restrict__ cw, const float* __restrict__ cb,
    int dil, float* __restrict__ acc)
{
    __shared__ float s0[4096];
    __shared__ float s1[4096];
    const int bc = blockIdx.x;        // b*32 + c
    const int b = bc >> 5, c = bc & 31;
    const int tid = threadIdx.x;
    const float* xin = x + ((size_t)(b*128 + c_off + c)) * 4096;
    float orig[16];
    #pragma unroll
    for (int kk=0;kk<16;++kk){ float v=xin[tid+kk*256]; orig[kk]=v; s0[tid+kk*256]=v; }
    __syncthreads();

    float w7[7];
    #pragma unroll
    for (int t=0;t<7;++t) w7[t]=mw_w[c*7+t];
    float bias = mw_b[c];
    float v[16];
    #pragma unroll
    for (int kk=0;kk<16;++kk){
        int p=tid+kk*256, i=p>>6, j=p&63;
        float s=bias;
        #pragma unroll
        for (int t=0;t<7;++t){ int jj=j+(t-3)*dil; if (jj>=0&&jj<64) s+=s0[i*64+jj]*w7[t]; }
        v[kk]=s;
    }
    #pragma unroll
    for (int kk=0;kk<16;++kk) s1[tid+kk*256]=v[kk];
    __syncthreads();

    #pragma unroll
    for (int t=0;t<7;++t) w7[t]=mh_w[c*7+t];
    bias = mh_b[c];
    #pragma unroll
    for (int kk=0;kk<16;++kk){
        int p=tid+kk*256, i=p>>6, j=p&63;
        float s=bias;
        #pragma unroll
        for (int t=0;t<7;++t){ int ii=i+(t-3)*dil; if (ii>=0&&ii<64) s+=s1[ii*64+j]*w7[t]; }
        v[kk]=s;
    }
    __syncthreads();
    #pragma unroll
    for (int kk=0;kk<16;++kk) s0[tid+kk*256]=v[kk];
    __syncthreads();

    float w9[9];
    #pragma unroll
    for (int t=0;t<9;++t) w9[t]=cw[c*9+t];
    bias = cb[c];
    float* aout = acc + ((size_t)(b*32+c))*4096;
    #pragma unroll
    for (int kk=0;kk<16;++kk){
        int p=tid+kk*256, i=p>>6, j=p&63;
        float s=bias;
        #pragma unroll
        for (int a=0;a<3;++a){
            int ii=i+(a-1)*dil; if (ii<0||ii>=64) continue;
            #pragma unroll
            for (int bb2=0;bb2<3;++bb2){
                int jj=j+(bb2-1)*dil; if (jj<0||jj>=64) continue;
                s += s0[ii*64+jj]*w9[a*3+bb2];
            }
        }
        aout[p] = s + orig[kk];
    }
}

// ---------------- LN(C=32) + in_proj (32 -> 128), split xc / z -------------------------
__global__ LB512 void lnproj_kernel(const float* __restrict__ acc,
    const float* __restrict__ ln_w, const float* __restrict__ ln_b,
    const float* __restrict__ in_proj_w,
    float* __restrict__ xc, float* __restrict__ z)
{
    __shared__ float s_a[32*65];
    const int b = blockIdx.x >> 6, lt = blockIdx.x & 63;
    const int l0 = lt*64;
    const int tid = threadIdx.x;
    const float* ab = acc + (size_t)b*32*4096 + l0;
    for (int i=tid;i<2048;i+=512){ int c=i>>6, j=i&63; s_a[c*65+j]=ab[(size_t)c*4096 + j]; }
    __syncthreads();
    const int l = tid & 63;
    const int g = __builtin_amdgcn_readfirstlane(tid >> 6);
    float v[32];
    float mu=0.f;
    #pragma unroll
    for (int c=0;c<32;++c){ v[c]=s_a[c*65+l]; mu+=v[c]; }
    mu *= (1.f/32.f);
    float var=0.f;
    #pragma unroll
    for (int c=0;c<32;++c){ float d2=v[c]-mu; var+=d2*d2; }
    var *= (1.f/32.f);
    float rs = rsqrtf(var+1e-5f);
    #pragma unroll
    for (int c=0;c<32;++c) v[c] = (v[c]-mu)*rs*ln_w[c] + ln_b[c];
    float* xcp = xc + (size_t)b*64*4096 + l0 + l;
    float* zp  = z  + (size_t)b*64*4096 + l0 + l;
    for (int e=g*16; e<g*16+16; ++e){
        const float* wr = in_proj_w + e*32;   // uniform rows -> scalar loads
        float s=0.f;
        #pragma unroll
        for (int c=0;c<32;++c) s += wr[c]*v[c];
        if (e<64) xcp[(size_t)e*4096]=s; else zp[(size_t)(e-64)*4096]=s;
    }
}

// ---------------- 3x3 dwconv (dil=1) + SiLU, fused transpose output --------------------
__global__ LB void conv3_kernel(const float* __restrict__ xc,
    const float* __restrict__ conv_w, const float* __restrict__ conv_b,
    float* __restrict__ xconv, float* __restrict__ xconvT)
{
    __shared__ float s0[4096];
    __shared__ float s1[64*65];
    const int bd = blockIdx.x;  // b*64 + d
    const int d = bd & 63;
    const int tid = threadIdx.x;
    const float* in = xc + (size_t)bd*4096;
    #pragma unroll
    for (int kk=0;kk<16;++kk) s0[tid+kk*256]=in[tid+kk*256];
    __syncthreads();
    float w9[9];
    #pragma unroll
    for (int t=0;t<9;++t) w9[t]=conv_w[d*9+t];
    float bias = conv_b[d];
    float* outp = xconv + (size_t)bd*4096;
    #pragma unroll
    for (int kk=0;kk<16;++kk){
        int p=tid+kk*256, i=p>>6, j=p&63;
        float s=bias;
        #pragma unroll
        for (int a=0;a<3;++a){
            int ii=i+a-1; if (ii<0||ii>=64) continue;
            #pragma unroll
            for (int bb2=0;bb2<3;++bb2){
                int jj=j+bb2-1; if (jj<0||jj>=64) continue;
                s += s0[ii*64+jj]*w9[a*3+bb2];
            }
        }
        s = silu_f(s);
        outp[p]=s;
        s1[i*65+j]=s;
    }
    __syncthreads();
    float* outT = xconvT + (size_t)bd*4096;
    #pragma unroll
    for (int kk=0;kk<16;++kk){ int p=tid+kk*256; outT[p] = s1[(p&63)*65 + (p>>6)]; }
}

// ---------------- fused x_proj + dt_proj + softplus + scan phase 1 ---------------------
// grid 2048 = tile = bk*64 + g ; 256 threads
__global__ LB void projscan1_kernel(const float* __restrict__ xconv, const float* __restrict__ xconvT,
    const float* __restrict__ x_proj_w, const float* __restrict__ dt_proj_w,
    const float* __restrict__ dt_proj_b, const float* __restrict__ A_log,
    float* __restrict__ Bsb, float* __restrict__ Csb, float* __restrict__ dts_g,
    float* __restrict__ Aprod, float* __restrict__ hloc)
{
    __shared__ float s_x[64*65];                    // [t][d]
    __shared__ __align__(16) float s_B[1024];       // [t][16]
    __shared__ __align__(16) float s_C[1024];       // [t][16]
    __shared__ float s_dts[128];                    // [t][2]
    const int blk = blockIdx.x;
    const int g = blk & 63, bk = blk >> 6;
    const int k = bk & 3, b = bk >> 2;
    const int tid = threadIdx.x;
    const int t0 = g*64;
    const float* src = (k & 1) ? xconvT : xconv;
    const float* sb = src + (size_t)b*64*4096;
    for (int i=tid;i<4096;i+=256){
        int d=i>>6, j=i&63;
        int col = (k&2) ? (4095-(t0+j)) : (t0+j);
        s_x[j*65+d] = sb[(size_t)d*4096 + col];     // [t][d], already in scan order
    }
    __syncthreads();

    // ---- proj GEMM (rows of x_proj_w), q-group owns 9 (or 7) rows ----
    {
        const int t = tid & 63;
        const int q = __builtin_amdgcn_readfirstlane(tid >> 6);
        const float* wp = x_proj_w + k*2176;
        float acc9[9];
        #pragma unroll
        for (int r=0;r<9;++r) acc9[r]=0.f;
        const int r0 = q*9;
        const int nr = (q==3)?7:9;
        for (int ch=0; ch<4; ++ch){
            float xv[16];
            #pragma unroll
            for (int i=0;i<16;++i) xv[i] = s_x[t*65 + ch*16 + i];
            #pragma unroll
            for (int r=0;r<9;++r){
                if (r < nr){
                    const float* wr = wp + (r0+r)*64 + ch*16;   // uniform -> scalar loads
                    float s=0.f;
                    #pragma unroll
                    for (int i=0;i<16;++i) s += wr[i]*xv[i];
                    acc9[r] += s;
                }
            }
        }
        #pragma unroll
        for (int r=0;r<9;++r){
            if (r<nr){
                int row = r0 + r;
                if (row < 2)       s_dts[t*2 + row]      = acc9[r];
                else if (row < 18) s_B[t*16 + (row-2)]   = acc9[r];
                else               s_C[t*16 + (row-18)]  = acc9[r];
            }
        }
    }
    __syncthreads();

    // ---- flush B/C/dts to global (coalesced) ----
    {
        const size_t tb = (size_t)blk*1024;
        for (int i=tid;i<1024;i+=256){ Bsb[tb+i]=s_B[i]; Csb[tb+i]=s_C[i]; }
        if (tid<128) dts_g[(size_t)blk*128 + tid] = s_dts[tid];
    }

    // ---- scan phase 1 (local): thread = (d = tid>>2, nb = (tid&3)*4) ----
    const int d = tid >> 2, nb = (tid & 3)*4;
    float4 Av = *(const float4*)(A_log + ((size_t)(k*64+d)*16 + nb));
    const float A0 = -__expf(Av.x)*LOG2E, A1 = -__expf(Av.y)*LOG2E,
                A2 = -__expf(Av.z)*LOG2E, A3 = -__expf(Av.w)*LOG2E;
    const float w0 = dt_proj_w[k*128 + d*2], w1 = dt_proj_w[k*128 + d*2 + 1];
    const float bb = dt_proj_b[k*64 + d];
    float h0=0,h1=0,h2=0,h3=0, p0=1,p1=1,p2=1,p3=1;
    #pragma unroll 4
    for (int t=0;t<64;++t){
        float dt0 = s_dts[t*2], dt1 = s_dts[t*2+1];
        float dlt = softplus_f(dt0*w0 + dt1*w1 + bb);
        float du  = dlt * s_x[t*65+d];
        float4 Bv = *(const float4*)&s_B[t*16+nb];
        float e0=exp2f(dlt*A0), e1=exp2f(dlt*A1), e2=exp2f(dlt*A2), e3=exp2f(dlt*A3);
        p0*=e0; p1*=e1; p2*=e2; p3*=e3;
        h0 = h0*e0 + du*Bv.x;
        h1 = h1*e1 + du*Bv.y;
        h2 = h2*e2 + du*Bv.z;
        h3 = h3*e3 + du*Bv.w;
    }
    const size_t o = (size_t)blk*256 + tid;
    ((float4*)Aprod)[o] = make_float4(p0,p1,p2,p3);
    ((float4*)hloc )[o] = make_float4(h0,h1,h2,h3);
}

// ---------------- scan phase 2: sequential chunk combine -> per-chunk entry states -----
__global__ LB void scan2_kernel(const float* __restrict__ Aprod,
    const float* __restrict__ hloc, float* __restrict__ hin)
{
    const int j = blockIdx.x*256 + threadIdx.x;   // 0..32767 : (b,k,dn)
    const int bk = j >> 10, dn = j & 1023;
    float h = 0.f;
    for (int g=0; g<64; ++g){
        const size_t o = ((size_t)bk*64 + g)*1024 + dn;
        hin[o] = h;
        h = Aprod[o]*h + hloc[o];
    }
}

// ---------------- scan phase 3: 1 wave per tile, lane = d, 16 n in registers -----------
// grid 512 blocks x 256 thr; wave w handles tile = blockIdx.x*4 + w
__global__ LB void scan3_kernel(const float* __restrict__ xconv, const float* __restrict__ xconvT,
    const float* __restrict__ Bsb, const float* __restrict__ Csb,
    const float* __restrict__ dts_g,
    const float* __restrict__ dt_proj_w, const float* __restrict__ dt_proj_b,
    const float* __restrict__ A_log, const float* __restrict__ Dp,
    const float* __restrict__ hin, float* __restrict__ outy)
{
    __shared__ __align__(16) float s_B[4][1024];
    __shared__ __align__(16) float s_C[4][1024];
    __shared__ float s_dts[4][128];
    __shared__ float s_y[4][64*17];
    const int w = threadIdx.x >> 6;
    const int lane = threadIdx.x & 63;            // = d
    const int tile = blockIdx.x*4 + w;
    const int g = tile & 63, bk = tile >> 6;
    const int k = bk & 3, b = bk >> 2;

    // per-wave staging (no cross-wave sharing -> no __syncthreads)
    {
        const float4* B4 = (const float4*)(Bsb + (size_t)tile*1024);
        const float4* C4 = (const float4*)(Csb + (size_t)tile*1024);
        float4* sB4 = (float4*)s_B[w];
        float4* sC4 = (float4*)s_C[w];
        #pragma unroll
        for (int qq=0;qq<4;++qq){ sB4[lane+64*qq]=B4[lane+64*qq]; sC4[lane+64*qq]=C4[lane+64*qq]; }
        s_dts[w][lane]      = dts_g[(size_t)tile*128 + lane];
        s_dts[w][lane+64]   = dts_g[(size_t)tile*128 + lane + 64];
    }
    const int d = lane;
    float A[16];
    {
        const float* Ab = A_log + (size_t)(k*64+d)*16;
        #pragma unroll
        for (int n=0;n<16;++n) A[n] = -__expf(Ab[n])*LOG2E;
    }
    float h[16];
    {
        const float4* hb = (const float4*)(hin + (size_t)tile*1024 + d*16);
        #pragma unroll
        for (int qq=0;qq<4;++qq){
            float4 v=hb[qq];
            h[qq*4+0]=v.x; h[qq*4+1]=v.y; h[qq*4+2]=v.z; h[qq*4+3]=v.w;
        }
    }
    const float w0 = dt_proj_w[k*128 + d*2], w1 = dt_proj_w[k*128 + d*2 + 1];
    const float bb = dt_proj_b[k*64 + d];
    const float Dv = Dp[k*64 + d];
    const float* up = ((k&1)?xconvT:xconv) + (size_t)(b*64+d)*4096;
    const float4* sB4 = (const float4*)s_B[w];
    const float4* sC4 = (const float4*)s_C[w];
    float* syw = s_y[w];

    for (int t4=0; t4<16; ++t4){
        float u4[4];
        if (k & 2){
            float4 r = *(const float4*)(up + (4092 - g*64 - t4*4));
            u4[0]=r.w; u4[1]=r.z; u4[2]=r.y; u4[3]=r.x;
        } else {
            float4 r = *(const float4*)(up + g*64 + t4*4);
            u4[0]=r.x; u4[1]=r.y; u4[2]=r.z; u4[3]=r.w;
        }
        #pragma unroll
        for (int j=0;j<4;++j){
            const int t = t4*4 + j;
            float dt0 = s_dts[w][t*2], dt1 = s_dts[w][t*2+1];
            float dlt = softplus_f(dt0*w0 + dt1*w1 + bb);
            float du  = dlt * u4[j];
            float y = 0.f;
            #pragma unroll
            for (int qq=0;qq<4;++qq){
                float4 Bv = sB4[t*4+qq];
                float4 Cv = sC4[t*4+qq];
                h[qq*4+0] = h[qq*4+0]*exp2f(dlt*A[qq*4+0]) + du*Bv.x;
                h[qq*4+1] = h[qq*4+1]*exp2f(dlt*A[qq*4+1]) + du*Bv.y;
                h[qq*4+2] = h[qq*4+2]*exp2f(dlt*A[qq*4+2]) + du*Bv.z;
                h[qq*4+3] = h[qq*4+3]*exp2f(dlt*A[qq*4+3]) + du*Bv.w;
                y += h[qq*4+0]*Cv.x + h[qq*4+1]*Cv.y + h[qq*4+2]*Cv.z + h[qq*4+3]*Cv.w;
            }
            syw[d*17 + (t & 15)] = y + Dv*u4[j];
        }
        if ((t4 & 3) == 3){
            const int tb = t4 >> 2;                 // 16-t block index
            const float* ob = nullptr; (void)ob;
            #pragma unroll
            for (int qq=0;qq<16;++qq){
                int i = qq*64 + lane;
                int dd = i >> 4, jj = i & 15;
                outy[((size_t)(bk*64+dd))*4096 + g*64 + tb*16 + jj] = syw[dd*17 + jj];
            }
        }
    }
}

// ---------------- transpose dir-1 / dir-3 planes of outy -------------------------------
__global__ LB void outyT_kernel(const float* __restrict__ outy, float* __restrict__ outyT)
{
    __shared__ float s[64*65];
    const int p = blockIdx.x;
    const int kk = p >> 9, bd = p & 511;
    const int b = bd >> 6, d = bd & 63;
    const float* ip = outy + ((size_t)(b*4 + (kk?3:1))*64 + d)*4096;
    const int tid = threadIdx.x;
    #pragma unroll
    for (int k2=0;k2<16;++k2){ int pp=tid+k2*256; s[(pp>>6)*65+(pp&63)] = ip[pp]; }
    __syncthreads();
    float* op = outyT + ((size_t)(kk*8+b)*64 + d)*4096;
    #pragma unroll
    for (int k2=0;k2<16;++k2){ int pp=tid+k2*256; op[pp] = s[(pp&63)*65 + (pp>>6)]; }
}

// ---------------- direction-combine + out LN + gate + out_proj + skip + BN + ReLU ------
__global__ LB512 void combine_kernel(const float* __restrict__ outy,
    const float* __restrict__ outyT,
    const float* __restrict__ z, const float* __restrict__ acc,
    const float* __restrict__ onw, const float* __restrict__ onb,
    const float* __restrict__ opw,
    const float* __restrict__ bn_g, const float* __restrict__ bn_b,
    const float* __restrict__ bn_m, const float* __restrict__ bn_v,
    int c_off, float* __restrict__ out)
{
    __shared__ float s_red[2][8][64];
    __shared__ float s_y[64*65];
    const int b = blockIdx.x >> 6, lt = blockIdx.x & 63;
    const int l0 = lt*64;
    const int tid = threadIdx.x;
    const int l = tid & 63;
    const int g = __builtin_amdgcn_readfirstlane(tid >> 6);
    const float* o0 = outy  + (size_t)(b*4+0)*64*4096;
    const float* o2 = outy  + (size_t)(b*4+2)*64*4096;
    const float* T1 = outyT + (size_t)(0*8+b)*64*4096;
    const float* T3 = outyT + (size_t)(1*8+b)*64*4096;
    const int lf = l0 + l;
    const int lr = 4095 - lf;
    float y[8];
    float psum=0.f, psq=0.f;
    #pragma unroll
    for (int i=0;i<8;++i){
        int d = g*8+i;
        float vv = o0[(size_t)d*4096 + lf] + o2[(size_t)d*4096 + lr]
                 + T1[(size_t)d*4096 + lf] + T3[(size_t)d*4096 + lr];
        y[i]=vv; psum+=vv; psq+=vv*vv;
    }
    s_red[0][g][l]=psum; s_red[1][g][l]=psq;
    __syncthreads();
    float mu=0.f, vsum=0.f;
    #pragma unroll
    for (int gg=0;gg<8;++gg){ mu += s_red[0][gg][l]; vsum += s_red[1][gg][l]; }
    mu *= (1.f/64.f);
    float var = vsum*(1.f/64.f) - mu*mu;
    float rs = rsqrtf(var + 1e-5f);
    const float* zp = z + (size_t)b*64*4096 + lf;
    #pragma unroll
    for (int i=0;i<8;++i){
        int d = g*8+i;
        float t2 = (y[i]-mu)*rs*onw[d] + onb[d];
        float zv = zp[(size_t)d*4096];
        s_y[l*65 + d] = t2 * silu_f(zv);
    }
    __syncthreads();
    float a4[4] = {0.f,0.f,0.f,0.f};
    for (int d=0; d<64; ++d){
        float xval = s_y[l*65+d];
        #pragma unroll
        for (int j=0;j<4;++j) a4[j] += opw[(g*4+j)*64+d]*xval;   // uniform -> scalar loads
    }
    const float* ap = acc + (size_t)b*32*4096 + lf;
    #pragma unroll
    for (int j=0;j<4;++j){
        int c = g*4+j, ch = c_off+c;
        float s = a4[j] + ap[(size_t)c*4096];
        float bnv = (s - bn_m[ch])*rsqrtf(bn_v[ch]+1e-5f)*bn_g[ch] + bn_b[ch];
        out[((size_t)b*128+ch)*4096 + lf] = fmaxf(bnv, 0.f);
    }
}

// ---------------- chunk 4 passthrough: BN + ReLU ----------------------------------------
__global__ LB void bnpass_kernel(const float* __restrict__ x,
    const float* __restrict__ bn_g, const float* __restrict__ bn_b,
    const float* __restrict__ bn_m, const float* __restrict__ bn_v,
    float* __restrict__ out)
{
    const int gid = blockIdx.x*256 + threadIdx.x;   // B*32*4096
    const int l = gid & 4095, bc = gid >> 12;
    const int c = bc & 31, b = bc >> 5;
    const int ch = 96 + c;
    const size_t idx = ((size_t)b*128+ch)*4096 + l;
    float v = x[idx];
    float r = (v - bn_m[ch])*rsqrtf(bn_v[ch]+1e-5f)*bn_g[ch] + bn_b[ch];
    out[idx] = fmaxf(r, 0.f);
}

extern "C" void kernel_launch(void* const* d_in, const int* in_sizes, int n_in,
                              void* d_out, int out_size, void* d_ws, size_t ws_size,
                              hipStream_t stream) {
    const float* x         = (const float*)d_in[0];
    const float* ln_w      = (const float*)d_in[19];
    const float* ln_b      = (const float*)d_in[20];
    const float* in_proj_w = (const float*)d_in[21];
    const float* conv_w    = (const float*)d_in[22];
    const float* conv_b    = (const float*)d_in[23];
    const float* x_proj_w  = (const float*)d_in[24];
    const float* dt_proj_w = (const float*)d_in[25];
    const float* dt_proj_b = (const float*)d_in[26];
    const float* A_log     = (const float*)d_in[27];
    const float* Dp        = (const float*)d_in[28];
    const float* onw       = (const float*)d_in[29];
    const float* onb       = (const float*)d_in[30];
    const float* opw       = (const float*)d_in[31];
    const float* bn_g      = (const float*)d_in[32];
    const float* bn_b      = (const float*)d_in[33];
    const float* bn_m      = (const float*)d_in[34];
    const float* bn_v      = (const float*)d_in[35];
    float* out = (float*)d_out;

    float* ws = (float*)d_ws;
    float* acc    = ws;                  // 1,048,576
    float* xc     = acc    + 1048576;    // 2,097,152
    float* z      = xc     + 2097152;    // 2,097,152
    float* xconv  = z      + 2097152;    // 2,097,152
    float* xconvT = xconv  + 2097152;    // 2,097,152
    float* Bsb    = xconvT + 2097152;    // 2,097,152
    float* Csb    = Bsb    + 2097152;    // 2,097,152
    float* dts_g  = Csb    + 2097152;    //   262,144
    float* Apr    = dts_g  + 262144;     // 2,097,152
    float* hlo    = Apr    + 2097152;    // 2,097,152
    float* hin    = hlo    + 2097152;    // 2,097,152
    float* outy   = hin    + 2097152;    // 8,388,608
    float* outyT  = outy   + 8388608;    // 4,194,304

    // chunk 4: raw passthrough with BN+ReLU
    bnpass_kernel<<<4096, 256, 0, stream>>>(x, bn_g, bn_b, bn_m, bn_v, out);

    for (int chunk=0; chunk<3; ++chunk){
        const int base = 1 + chunk*6;
        const float* mh_w = (const float*)d_in[base+0];
        const float* mh_b = (const float*)d_in[base+1];
        const float* mw_w = (const float*)d_in[base+2];
        const float* mw_b = (const float*)d_in[base+3];
        const float* c_w  = (const float*)d_in[base+4];
        const float* c_b  = (const float*)d_in[base+5];
        const int dil = chunk + 1;
        const int c_off = chunk*32;

        axial_kernel<<<256, 256, 0, stream>>>(x, c_off, mh_w, mh_b, mw_w, mw_b, c_w, c_b, dil, acc);
        lnproj_kernel<<<512, 512, 0, stream>>>(acc, ln_w, ln_b, in_proj_w, xc, z);
        conv3_kernel<<<512, 256, 0, stream>>>(xc, conv_w, conv_b, xconv, xconvT);
        projscan1_kernel<<<2048, 256, 0, stream>>>(xconv, xconvT, x_proj_w, dt_proj_w, dt_proj_b,
                                                   A_log, Bsb, Csb, dts_g, Apr, hlo);
        scan2_kernel<<<128, 256, 0, stream>>>(Apr, hlo, hin);
        scan3_kernel<<<512, 256, 0, stream>>>(xconv, xconvT, Bsb, Csb, dts_g,
                                              dt_proj_w, dt_proj_b, A_log, Dp, hin, outy);
        outyT_kernel<<<1024, 256, 0, stream>>>(outy, outyT);
        combine_kernel<<<512, 512, 0, stream>>>(outy, outyT, z, acc, onw, onb, opw,
                                                bn_g, bn_b, bn_m, bn_v, c_off, out);
    }
}

// Round 4
// 512.943 us; speedup vs baseline: 1.8722x; 1.1618x over previous
//
#include <hip/hip_runtime.h>
#include <math.h>

#define LB __launch_bounds__(256)
#define LB512 __launch_bounds__(512)

// B=8, DIM=128, C=32, DI=64, H=W=64, L=4096, K=4, N=16, R=2, G=64 chunks of 64
#define LOG2E 1.44269504088896340736f
static __device__ __forceinline__ float silu_f(float x){ return x / (1.f + __expf(-x)); }
static __device__ __forceinline__ float softplus_f(float x){
    return (x > 20.f) ? x : __logf(1.f + __expf(x));
}

struct AxialArgs { const float* w[18]; };

// ---------------- axial depthwise (all 3 chunks batched): mw(1x7)->mh(7x1)->c(3x3)+skip
__global__ LB void axial_kernel(const float* __restrict__ x, AxialArgs args,
                                float* __restrict__ acc)
{
    __shared__ float s0[4096];
    __shared__ float s1[4096];
    const int chunk = blockIdx.x >> 8;
    const int bc = blockIdx.x & 255;      // b*32 + c
    const int b = bc >> 5, c = bc & 31;
    const int dil = chunk + 1;
    const float* mh_w = args.w[chunk*6+0];
    const float* mh_b = args.w[chunk*6+1];
    const float* mw_w = args.w[chunk*6+2];
    const float* mw_b = args.w[chunk*6+3];
    const float* cw   = args.w[chunk*6+4];
    const float* cb   = args.w[chunk*6+5];
    const int tid = threadIdx.x;
    const float* xin = x + ((size_t)(b*128 + chunk*32 + c)) * 4096;
    float orig[16];
    #pragma unroll
    for (int kk=0;kk<16;++kk){ float v=xin[tid+kk*256]; orig[kk]=v; s0[tid+kk*256]=v; }
    __syncthreads();

    float w7[7];
    #pragma unroll
    for (int t=0;t<7;++t) w7[t]=mw_w[c*7+t];
    float bias = mw_b[c];
    float v[16];
    #pragma unroll
    for (int kk=0;kk<16;++kk){
        int p=tid+kk*256, i=p>>6, j=p&63;
        float s=bias;
        #pragma unroll
        for (int t=0;t<7;++t){ int jj=j+(t-3)*dil; if (jj>=0&&jj<64) s+=s0[i*64+jj]*w7[t]; }
        v[kk]=s;
    }
    #pragma unroll
    for (int kk=0;kk<16;++kk) s1[tid+kk*256]=v[kk];
    __syncthreads();

    #pragma unroll
    for (int t=0;t<7;++t) w7[t]=mh_w[c*7+t];
    bias = mh_b[c];
    #pragma unroll
    for (int kk=0;kk<16;++kk){
        int p=tid+kk*256, i=p>>6, j=p&63;
        float s=bias;
        #pragma unroll
        for (int t=0;t<7;++t){ int ii=i+(t-3)*dil; if (ii>=0&&ii<64) s+=s1[ii*64+j]*w7[t]; }
        v[kk]=s;
    }
    __syncthreads();
    #pragma unroll
    for (int kk=0;kk<16;++kk) s0[tid+kk*256]=v[kk];
    __syncthreads();

    float w9[9];
    #pragma unroll
    for (int t=0;t<9;++t) w9[t]=cw[c*9+t];
    bias = cb[c];
    float* aout = acc + (size_t)chunk*1048576 + ((size_t)(b*32+c))*4096;
    #pragma unroll
    for (int kk=0;kk<16;++kk){
        int p=tid+kk*256, i=p>>6, j=p&63;
        float s=bias;
        #pragma unroll
        for (int a=0;a<3;++a){
            int ii=i+(a-1)*dil; if (ii<0||ii>=64) continue;
            #pragma unroll
            for (int bb2=0;bb2<3;++bb2){
                int jj=j+(bb2-1)*dil; if (jj<0||jj>=64) continue;
                s += s0[ii*64+jj]*w9[a*3+bb2];
            }
        }
        aout[p] = s + orig[kk];
    }
}

// ---------------- LN(C=32) + in_proj (32 -> 128), split xc / z -------------------------
__global__ LB512 void lnproj_kernel(const float* __restrict__ acc,
    const float* __restrict__ ln_w, const float* __restrict__ ln_b,
    const float* __restrict__ in_proj_w,
    float* __restrict__ xc, float* __restrict__ z)
{
    __shared__ float s_a[32*65];
    const int b = blockIdx.x >> 6, lt = blockIdx.x & 63;
    const int l0 = lt*64;
    const int tid = threadIdx.x;
    const float* ab = acc + (size_t)b*32*4096 + l0;
    for (int i=tid;i<2048;i+=512){ int c=i>>6, j=i&63; s_a[c*65+j]=ab[(size_t)c*4096 + j]; }
    __syncthreads();
    const int l = tid & 63;
    const int g = __builtin_amdgcn_readfirstlane(tid >> 6);
    float v[32];
    float mu=0.f;
    #pragma unroll
    for (int c=0;c<32;++c){ v[c]=s_a[c*65+l]; mu+=v[c]; }
    mu *= (1.f/32.f);
    float var=0.f;
    #pragma unroll
    for (int c=0;c<32;++c){ float d2=v[c]-mu; var+=d2*d2; }
    var *= (1.f/32.f);
    float rs = rsqrtf(var+1e-5f);
    #pragma unroll
    for (int c=0;c<32;++c) v[c] = (v[c]-mu)*rs*ln_w[c] + ln_b[c];
    float* xcp = xc + (size_t)b*64*4096 + l0 + l;
    float* zp  = z  + (size_t)b*64*4096 + l0 + l;
    for (int e=g*16; e<g*16+16; ++e){
        const float* wr = in_proj_w + e*32;   // uniform rows -> scalar loads
        float s=0.f;
        #pragma unroll
        for (int c=0;c<32;++c) s += wr[c]*v[c];
        if (e<64) xcp[(size_t)e*4096]=s; else zp[(size_t)(e-64)*4096]=s;
    }
}

// ---------------- 3x3 dwconv (dil=1) + SiLU, fused transpose output --------------------
__global__ LB void conv3_kernel(const float* __restrict__ xc,
    const float* __restrict__ conv_w, const float* __restrict__ conv_b,
    float* __restrict__ xconv, float* __restrict__ xconvT)
{
    __shared__ float s0[4096];
    __shared__ float s1[64*65];
    const int bd = blockIdx.x;  // b*64 + d
    const int d = bd & 63;
    const int tid = threadIdx.x;
    const float* in = xc + (size_t)bd*4096;
    #pragma unroll
    for (int kk=0;kk<16;++kk) s0[tid+kk*256]=in[tid+kk*256];
    __syncthreads();
    float w9[9];
    #pragma unroll
    for (int t=0;t<9;++t) w9[t]=conv_w[d*9+t];
    float bias = conv_b[d];
    float* outp = xconv + (size_t)bd*4096;
    #pragma unroll
    for (int kk=0;kk<16;++kk){
        int p=tid+kk*256, i=p>>6, j=p&63;
        float s=bias;
        #pragma unroll
        for (int a=0;a<3;++a){
            int ii=i+a-1; if (ii<0||ii>=64) continue;
            #pragma unroll
            for (int bb2=0;bb2<3;++bb2){
                int jj=j+bb2-1; if (jj<0||jj>=64) continue;
                s += s0[ii*64+jj]*w9[a*3+bb2];
            }
        }
        s = silu_f(s);
        outp[p]=s;
        s1[i*65+j]=s;
    }
    __syncthreads();
    float* outT = xconvT + (size_t)bd*4096;
    #pragma unroll
    for (int kk=0;kk<16;++kk){ int p=tid+kk*256; outT[p] = s1[(p&63)*65 + (p>>6)]; }
}

// ---------------- fused x_proj + dt_proj + softplus + scan phase 1 ---------------------
// grid 2048 = tile = bk*64 + g ; 256 threads
__global__ LB void projscan1_kernel(const float* __restrict__ xconv, const float* __restrict__ xconvT,
    const float* __restrict__ x_proj_w, const float* __restrict__ dt_proj_w,
    const float* __restrict__ dt_proj_b, const float* __restrict__ A_log,
    float* __restrict__ Bsb, float* __restrict__ Csb, float* __restrict__ dts_g,
    float* __restrict__ Ssum, float* __restrict__ hloc)
{
    __shared__ float s_x[64*65];                    // [t][d]: x, overwritten with du
    __shared__ float s_dlt[64*65];                  // [t][d] dlt; first 1024 alias s_C
    __shared__ __align__(16) float s_B[1024];       // [t][16]
    __shared__ float s_dts[128];                    // [t][2]
    __shared__ float s_Spart[4][64];
    float* s_C = s_dlt;                             // liveness-disjoint alias
    const int blk = blockIdx.x;
    const int g = blk & 63, bk = blk >> 6;
    const int k = bk & 3, b = bk >> 2;
    const int tid = threadIdx.x;
    const int t0 = g*64;
    const float* src = (k & 1) ? xconvT : xconv;
    const float* sb = src + (size_t)b*64*4096;
    for (int i=tid;i<4096;i+=256){
        int d=i>>6, j=i&63;
        int col = (k&2) ? (4095-(t0+j)) : (t0+j);
        s_x[j*65+d] = sb[(size_t)d*4096 + col];     // [t][d], scan order
    }
    __syncthreads();

    // ---- proj GEMM ----
    {
        const int t = tid & 63;
        const int q = __builtin_amdgcn_readfirstlane(tid >> 6);
        const float* wp = x_proj_w + k*2176;
        float acc9[9];
        #pragma unroll
        for (int r=0;r<9;++r) acc9[r]=0.f;
        const int r0 = q*9;
        const int nr = (q==3)?7:9;
        for (int ch=0; ch<4; ++ch){
            float xv[16];
            #pragma unroll
            for (int i=0;i<16;++i) xv[i] = s_x[t*65 + ch*16 + i];
            #pragma unroll
            for (int r=0;r<9;++r){
                if (r < nr){
                    const float* wr = wp + (r0+r)*64 + ch*16;   // uniform -> scalar loads
                    float s=0.f;
                    #pragma unroll
                    for (int i=0;i<16;++i) s += wr[i]*xv[i];
                    acc9[r] += s;
                }
            }
        }
        #pragma unroll
        for (int r=0;r<9;++r){
            if (r<nr){
                int row = r0 + r;
                if (row < 2)       s_dts[t*2 + row]      = acc9[r];
                else if (row < 18) s_B[t*16 + (row-2)]   = acc9[r];
                else               s_C[t*16 + (row-18)]  = acc9[r];
            }
        }
    }
    __syncthreads();

    // ---- flush B/C/dts (coalesced) ----
    {
        const size_t tb = (size_t)blk*1024;
        for (int i=tid;i<1024;i+=256){ Bsb[tb+i]=s_B[i]; Csb[tb+i]=s_C[i]; }
        if (tid<128) dts_g[(size_t)blk*128 + tid] = s_dts[tid];
    }
    __syncthreads();   // all s_C reads done before dlt overwrite

    // ---- precompute dlt / du (in place) / per-d delta-sum ----
    {
        const int d_ = tid & 63, part = tid >> 6;
        const float w0 = dt_proj_w[k*128 + d_*2], w1 = dt_proj_w[k*128 + d_*2 + 1];
        const float bb = dt_proj_b[k*64 + d_];
        float Sp = 0.f;
        #pragma unroll
        for (int i=0;i<16;++i){
            const int t = part*16 + i;
            float dlt = softplus_f(s_dts[t*2]*w0 + s_dts[t*2+1]*w1 + bb);
            s_dlt[t*65 + d_] = dlt;
            s_x[t*65 + d_] *= dlt;        // du
            Sp += dlt;
        }
        s_Spart[part][d_] = Sp;
    }
    __syncthreads();
    if (tid < 64){
        Ssum[(size_t)blk*64 + tid] = s_Spart[0][tid]+s_Spart[1][tid]
                                   + s_Spart[2][tid]+s_Spart[3][tid];
    }

    // ---- local scan: thread = (d = tid>>2, nb = (tid&3)*4) ----
    const int d = tid >> 2, nb = (tid & 3)*4;
    float4 Av = *(const float4*)(A_log + ((size_t)(k*64+d)*16 + nb));
    const float A0 = -__expf(Av.x)*LOG2E, A1 = -__expf(Av.y)*LOG2E,
                A2 = -__expf(Av.z)*LOG2E, A3 = -__expf(Av.w)*LOG2E;
    float h0=0,h1=0,h2=0,h3=0;
    #pragma unroll 4
    for (int t=0;t<64;++t){
        float dlt = s_dlt[t*65+d];
        float du  = s_x[t*65+d];
        float4 Bv = *(const float4*)&s_B[t*16+nb];
        h0 = h0*exp2f(dlt*A0) + du*Bv.x;
        h1 = h1*exp2f(dlt*A1) + du*Bv.y;
        h2 = h2*exp2f(dlt*A2) + du*Bv.z;
        h3 = h3*exp2f(dlt*A3) + du*Bv.w;
    }
    ((float4*)hloc)[(size_t)blk*256 + tid] = make_float4(h0,h1,h2,h3);
}

// ---------------- scan phase 2: chunk combine; Aprod = exp2(A * S_chunk) ---------------
__global__ LB void scan2_kernel(const float* __restrict__ Ssum,
    const float* __restrict__ hloc, const float* __restrict__ A_log,
    float* __restrict__ hin)
{
    const int j = blockIdx.x*256 + threadIdx.x;   // 0..32767 : (b,k,dn)
    const int bk = j >> 10, dn = j & 1023;
    const int k = bk & 3, d = dn >> 4, n = dn & 15;
    const float A = -__expf(A_log[(size_t)(k*64+d)*16 + n]) * LOG2E;
    float h = 0.f;
    for (int g=0; g<64; ++g){
        const size_t o = ((size_t)bk*64 + g)*1024 + dn;
        hin[o] = h;
        float S = Ssum[((size_t)bk*64 + g)*64 + d];
        h = exp2f(A*S)*h + hloc[o];
    }
}

// ---------------- scan phase 3: 1 wave per tile, lane = d, 16 n in registers -----------
__global__ LB void scan3_kernel(const float* __restrict__ xconv, const float* __restrict__ xconvT,
    const float* __restrict__ Bsb, const float* __restrict__ Csb,
    const float* __restrict__ dts_g,
    const float* __restrict__ dt_proj_w, const float* __restrict__ dt_proj_b,
    const float* __restrict__ A_log, const float* __restrict__ Dp,
    const float* __restrict__ hin, float* __restrict__ outy)
{
    __shared__ __align__(16) float s_B[4][1024];
    __shared__ __align__(16) float s_C[4][1024];
    __shared__ float s_dts[4][128];
    __shared__ float s_y[4][64*17];
    const int w = threadIdx.x >> 6;
    const int lane = threadIdx.x & 63;            // = d
    const int tile = blockIdx.x*4 + w;
    const int g = tile & 63, bk = tile >> 6;
    const int k = bk & 3, b = bk >> 2;

    {
        const float4* B4 = (const float4*)(Bsb + (size_t)tile*1024);
        const float4* C4 = (const float4*)(Csb + (size_t)tile*1024);
        float4* sB4 = (float4*)s_B[w];
        float4* sC4 = (float4*)s_C[w];
        #pragma unroll
        for (int qq=0;qq<4;++qq){ sB4[lane+64*qq]=B4[lane+64*qq]; sC4[lane+64*qq]=C4[lane+64*qq]; }
        s_dts[w][lane]      = dts_g[(size_t)tile*128 + lane];
        s_dts[w][lane+64]   = dts_g[(size_t)tile*128 + lane + 64];
    }
    const int d = lane;
    float A[16];
    {
        const float* Ab = A_log + (size_t)(k*64+d)*16;
        #pragma unroll
        for (int n=0;n<16;++n) A[n] = -__expf(Ab[n])*LOG2E;
    }
    float h[16];
    {
        const float4* hb = (const float4*)(hin + (size_t)tile*1024 + d*16);
        #pragma unroll
        for (int qq=0;qq<4;++qq){
            float4 v=hb[qq];
            h[qq*4+0]=v.x; h[qq*4+1]=v.y; h[qq*4+2]=v.z; h[qq*4+3]=v.w;
        }
    }
    const float w0 = dt_proj_w[k*128 + d*2], w1 = dt_proj_w[k*128 + d*2 + 1];
    const float bb = dt_proj_b[k*64 + d];
    const float Dv = Dp[k*64 + d];
    const float* up = ((k&1)?xconvT:xconv) + (size_t)(b*64+d)*4096;
    const float4* sB4 = (const float4*)s_B[w];
    const float4* sC4 = (const float4*)s_C[w];
    float* syw = s_y[w];

    for (int t4=0; t4<16; ++t4){
        float u4[4];
        if (k & 2){
            float4 r = *(const float4*)(up + (4092 - g*64 - t4*4));
            u4[0]=r.w; u4[1]=r.z; u4[2]=r.y; u4[3]=r.x;
        } else {
            float4 r = *(const float4*)(up + g*64 + t4*4);
            u4[0]=r.x; u4[1]=r.y; u4[2]=r.z; u4[3]=r.w;
        }
        #pragma unroll
        for (int j=0;j<4;++j){
            const int t = t4*4 + j;
            float dt0 = s_dts[w][t*2], dt1 = s_dts[w][t*2+1];
            float dlt = softplus_f(dt0*w0 + dt1*w1 + bb);
            float du  = dlt * u4[j];
            float y = 0.f;
            #pragma unroll
            for (int qq=0;qq<4;++qq){
                float4 Bv = sB4[t*4+qq];
                float4 Cv = sC4[t*4+qq];
                h[qq*4+0] = h[qq*4+0]*exp2f(dlt*A[qq*4+0]) + du*Bv.x;
                h[qq*4+1] = h[qq*4+1]*exp2f(dlt*A[qq*4+1]) + du*Bv.y;
                h[qq*4+2] = h[qq*4+2]*exp2f(dlt*A[qq*4+2]) + du*Bv.z;
                h[qq*4+3] = h[qq*4+3]*exp2f(dlt*A[qq*4+3]) + du*Bv.w;
                y += h[qq*4+0]*Cv.x + h[qq*4+1]*Cv.y + h[qq*4+2]*Cv.z + h[qq*4+3]*Cv.w;
            }
            syw[d*17 + (t & 15)] = y + Dv*u4[j];
        }
        if ((t4 & 3) == 3){
            const int tb = t4 >> 2;
            #pragma unroll
            for (int qq=0;qq<16;++qq){
                int i = qq*64 + lane;
                int dd = i >> 4, jj = i & 15;
                outy[((size_t)(bk*64+dd))*4096 + g*64 + tb*16 + jj] = syw[dd*17 + jj];
            }
        }
    }
}

// ---------------- transpose dir-1 / dir-3 planes of outy -------------------------------
__global__ LB void outyT_kernel(const float* __restrict__ outy, float* __restrict__ outyT)
{
    __shared__ float s[64*65];
    const int p = blockIdx.x;
    const int kk = p >> 9, bd = p & 511;
    const int b = bd >> 6, d = bd & 63;
    const float* ip = outy + ((size_t)(b*4 + (kk?3:1))*64 + d)*4096;
    const int tid = threadIdx.x;
    #pragma unroll
    for (int k2=0;k2<16;++k2){ int pp=tid+k2*256; s[(pp>>6)*65+(pp&63)] = ip[pp]; }
    __syncthreads();
    float* op = outyT + ((size_t)(kk*8+b)*64 + d)*4096;
    #pragma unroll
    for (int k2=0;k2<16;++k2){ int pp=tid+k2*256; op[pp] = s[(pp&63)*65 + (pp>>6)]; }
}

// ---------------- direction-combine + out LN + gate + out_proj + skip + BN + ReLU ------
__global__ LB512 void combine_kernel(const float* __restrict__ outy,
    const float* __restrict__ outyT,
    const float* __restrict__ z, const float* __restrict__ acc,
    const float* __restrict__ onw, const float* __restrict__ onb,
    const float* __restrict__ opw,
    const float* __restrict__ bn_g, const float* __restrict__ bn_b,
    const float* __restrict__ bn_m, const float* __restrict__ bn_v,
    int c_off, float* __restrict__ out)
{
    __shared__ float s_red[2][8][64];
    __shared__ float s_y[64*65];
    const int b = blockIdx.x >> 6, lt = blockIdx.x & 63;
    const int l0 = lt*64;
    const int tid = threadIdx.x;
    const int l = tid & 63;
    const int g = __builtin_amdgcn_readfirstlane(tid >> 6);
    const float* o0 = outy  + (size_t)(b*4+0)*64*4096;
    const float* o2 = outy  + (size_t)(b*4+2)*64*4096;
    const float* T1 = outyT + (size_t)(0*8+b)*64*4096;
    const float* T3 = outyT + (size_t)(1*8+b)*64*4096;
    const int lf = l0 + l;
    const int lr = 4095 - lf;
    float y[8];
    float psum=0.f, psq=0.f;
    #pragma unroll
    for (int i=0;i<8;++i){
        int d = g*8+i;
        float vv = o0[(size_t)d*4096 + lf] + o2[(size_t)d*4096 + lr]
                 + T1[(size_t)d*4096 + lf] + T3[(size_t)d*4096 + lr];
        y[i]=vv; psum+=vv; psq+=vv*vv;
    }
    s_red[0][g][l]=psum; s_red[1][g][l]=psq;
    __syncthreads();
    float mu=0.f, vsum=0.f;
    #pragma unroll
    for (int gg=0;gg<8;++gg){ mu += s_red[0][gg][l]; vsum += s_red[1][gg][l]; }
    mu *= (1.f/64.f);
    float var = vsum*(1.f/64.f) - mu*mu;
    float rs = rsqrtf(var + 1e-5f);
    const float* zp = z + (size_t)b*64*4096 + lf;
    #pragma unroll
    for (int i=0;i<8;++i){
        int d = g*8+i;
        float t2 = (y[i]-mu)*rs*onw[d] + onb[d];
        float zv = zp[(size_t)d*4096];
        s_y[l*65 + d] = t2 * silu_f(zv);
    }
    __syncthreads();
    float a4[4] = {0.f,0.f,0.f,0.f};
    for (int d=0; d<64; ++d){
        float xval = s_y[l*65+d];
        #pragma unroll
        for (int j=0;j<4;++j) a4[j] += opw[(g*4+j)*64+d]*xval;   // uniform -> scalar loads
    }
    const float* ap = acc + (size_t)b*32*4096 + lf;
    #pragma unroll
    for (int j=0;j<4;++j){
        int c = g*4+j, ch = c_off+c;
        float s = a4[j] + ap[(size_t)c*4096];
        float bnv = (s - bn_m[ch])*rsqrtf(bn_v[ch]+1e-5f)*bn_g[ch] + bn_b[ch];
        out[((size_t)b*128+ch)*4096 + lf] = fmaxf(bnv, 0.f);
    }
}

// ---------------- chunk 4 passthrough: BN + ReLU ----------------------------------------
__global__ LB void bnpass_kernel(const float* __restrict__ x,
    const float* __restrict__ bn_g, const float* __restrict__ bn_b,
    const float* __restrict__ bn_m, const float* __restrict__ bn_v,
    float* __restrict__ out)
{
    const int gid = blockIdx.x*256 + threadIdx.x;   // B*32*4096
    const int l = gid & 4095, bc = gid >> 12;
    const int c = bc & 31, b = bc >> 5;
    const int ch = 96 + c;
    const size_t idx = ((size_t)b*128+ch)*4096 + l;
    float v = x[idx];
    float r = (v - bn_m[ch])*rsqrtf(bn_v[ch]+1e-5f)*bn_g[ch] + bn_b[ch];
    out[idx] = fmaxf(r, 0.f);
}

extern "C" void kernel_launch(void* const* d_in, const int* in_sizes, int n_in,
                              void* d_out, int out_size, void* d_ws, size_t ws_size,
                              hipStream_t stream) {
    const float* x         = (const float*)d_in[0];
    const float* ln_w      = (const float*)d_in[19];
    const float* ln_b      = (const float*)d_in[20];
    const float* in_proj_w = (const float*)d_in[21];
    const float* conv_w    = (const float*)d_in[22];
    const float* conv_b    = (const float*)d_in[23];
    const float* x_proj_w  = (const float*)d_in[24];
    const float* dt_proj_w = (const float*)d_in[25];
    const float* dt_proj_b = (const float*)d_in[26];
    const float* A_log     = (const float*)d_in[27];
    const float* Dp        = (const float*)d_in[28];
    const float* onw       = (const float*)d_in[29];
    const float* onb       = (const float*)d_in[30];
    const float* opw       = (const float*)d_in[31];
    const float* bn_g      = (const float*)d_in[32];
    const float* bn_b      = (const float*)d_in[33];
    const float* bn_m      = (const float*)d_in[34];
    const float* bn_v      = (const float*)d_in[35];
    float* out = (float*)d_out;

    float* ws = (float*)d_ws;
    float* acc    = ws;                  // 3 x 1,048,576 (per chunk)
    float* xc     = acc    + 3145728;    // 2,097,152
    float* z      = xc     + 2097152;    // 2,097,152
    float* xconv  = z      + 2097152;    // 2,097,152
    float* xconvT = xconv  + 2097152;    // 2,097,152
    float* Bsb    = xconvT + 2097152;    // 2,097,152
    float* Csb    = Bsb    + 2097152;    // 2,097,152
    float* dts_g  = Csb    + 2097152;    //   262,144
    float* Ssum   = dts_g  + 262144;     //   131,072
    float* hlo    = Ssum   + 131072;     // 2,097,152
    float* hin    = hlo    + 2097152;    // 2,097,152
    float* outy   = hin    + 2097152;    // 8,388,608
    float* outyT  = outy   + 8388608;    // 4,194,304

    // chunk 4: raw passthrough with BN+ReLU
    bnpass_kernel<<<4096, 256, 0, stream>>>(x, bn_g, bn_b, bn_m, bn_v, out);

    // all 3 chunks' axial stacks batched
    AxialArgs aargs;
    for (int chunk=0; chunk<3; ++chunk)
        for (int jj=0; jj<6; ++jj)
            aargs.w[chunk*6+jj] = (const float*)d_in[1 + chunk*6 + jj];
    axial_kernel<<<768, 256, 0, stream>>>(x, aargs, acc);

    for (int chunk=0; chunk<3; ++chunk){
        const int c_off = chunk*32;
        const float* acc_c = acc + (size_t)chunk*1048576;

        lnproj_kernel<<<512, 512, 0, stream>>>(acc_c, ln_w, ln_b, in_proj_w, xc, z);
        conv3_kernel<<<512, 256, 0, stream>>>(xc, conv_w, conv_b, xconv, xconvT);
        projscan1_kernel<<<2048, 256, 0, stream>>>(xconv, xconvT, x_proj_w, dt_proj_w, dt_proj_b,
                                                   A_log, Bsb, Csb, dts_g, Ssum, hlo);
        scan2_kernel<<<128, 256, 0, stream>>>(Ssum, hlo, A_log, hin);
        scan3_kernel<<<512, 256, 0, stream>>>(xconv, xconvT, Bsb, Csb, dts_g,
                                              dt_proj_w, dt_proj_b, A_log, Dp, hin, outy);
        outyT_kernel<<<1024, 256, 0, stream>>>(outy, outyT);
        combine_kernel<<<512, 512, 0, stream>>>(outy, outyT, z, acc_c, onw, onb, opw,
                                                bn_g, bn_b, bn_m, bn_v, c_off, out);
    }
}